// Round 4
// baseline (1533.046 us; speedup 1.0000x reference)
//
#include <hip/hip_runtime.h>
#include <hip/hip_fp16.h>

#define N_ 50000
#define E_ 800000
#define T_ 800000
#define G_ 64
#define H_ 128

// bucket sort geometry: 64 cols per bucket, 8 XCD-affine sub-buckets each
#define NBK 782            // ceil(N/64)
#define NSB (NBK * 8)      // 6256 sub-buckets
#define CAPS 512           // entries per sub-bucket (mean ~128)
#define CHUNK 4096         // elements per k_bucket block
#define EB ((E_ + CHUNK - 1) / CHUNK)   // 196
#define TB ((T_ + CHUNK - 1) / CHUNK)   // 196
#define XSLOT 16           // extra-reduction atomic slots

#define GEMMG2 ((N_ + 31) / 32)     // 1563 MFMA blocks (128 thr / 32 rows)
#define NG2 ((N_ + 1) / 2)          // 25000 gather blocks (128 thr / 2 nodes)
#define NIX ((N_ * 16 + 127) / 128) // 6250 init_x blocks
#define SVG ((N_ + 3) / 4)          // 12500 sv4 blocks (128 thr / 4 nodes)
#define EG ((E_ + 255) / 256)
#define TG ((T_ + 255) / 256)

typedef __attribute__((ext_vector_type(8))) short bf16x8;
typedef __attribute__((ext_vector_type(4))) float f32x4;
typedef _Float16 f16x2 __attribute__((ext_vector_type(2)));

__device__ __forceinline__ float siluf(float v) {
    return __fdividef(v, 1.0f + __expf(-v));
}

__device__ __forceinline__ unsigned short f2bf(float f) {
    unsigned int u = __float_as_uint(f);
    u += 0x7fffu + ((u >> 16) & 1u);
    return (unsigned short)(u >> 16);
}
__device__ __forceinline__ unsigned int f2bf2(float a, float b) {
    return (unsigned int)f2bf(a) | ((unsigned int)f2bf(b) << 16);
}
__device__ __forceinline__ float bf2f(unsigned short h) {
    return __uint_as_float(((unsigned int)h) << 16);
}
__device__ __forceinline__ float2 bf2x2(unsigned int p) {
    return make_float2(__uint_as_float(p << 16), __uint_as_float(p & 0xffff0000u));
}
__device__ __forceinline__ float fdot2f(f16x2 a, f16x2 b, float c) {
    return __builtin_amdgcn_fdot2(a, b, c, false);
}

// ================= CSR build =================
__global__ __launch_bounds__(256) void k_bucket(const int* __restrict__ ecol,
                                                const int* __restrict__ trip,
                                                int* bcntE, unsigned int* __restrict__ ebkt,
                                                int* bcntT, unsigned int* __restrict__ tbkt) {
    __shared__ int hist[NBK];
    __shared__ int bbase[NBK];
    int blk = blockIdx.x;
    bool isE = blk < EB;
    int ebase = (isE ? blk : blk - EB) * CHUNK;
    const int nElem = isE ? E_ : T_;
    int r = blk & 7;
    int* bcnt = isE ? bcntE : bcntT;
    unsigned int* bkt = isE ? ebkt : tbkt;
    int tid = threadIdx.x;

    for (int i = tid; i < NBK; i += 256) hist[i] = 0;
    __syncthreads();

    int cols[16];
    #pragma unroll
    for (int u = 0; u < 16; ++u) {
        int idx = ebase + u * 256 + tid;
        int c = -1;
        if (idx < nElem) c = isE ? ecol[idx] : trip[3 * idx + 1];
        cols[u] = c;
        if (c >= 0) atomicAdd(&hist[c >> 6], 1);
    }
    __syncthreads();

    for (int b = tid; b < NBK; b += 256) {
        int c = hist[b];
        bbase[b] = c ? atomicAdd(&bcnt[b * 8 + r], c) : 0;
        hist[b] = 0;
    }
    __syncthreads();

    #pragma unroll
    for (int u = 0; u < 16; ++u) {
        int c = cols[u];
        if (c >= 0) {
            int bk = c >> 6;
            int off = atomicAdd(&hist[bk], 1);
            int pos = bbase[bk] + off;
            if (pos < CAPS) {
                int idx = ebase + u * 256 + tid;
                bkt[(size_t)(bk * 8 + r) * CAPS + pos] =
                    ((unsigned int)idx << 6) | (unsigned int)(c & 63);
            }
        }
    }
}

__global__ __launch_bounds__(1024) void k_scanB(const int* __restrict__ bcntE, int* bktbaseE,
                                                const int* __restrict__ bcntT, int* bktbaseT) {
    const int* bcnt = (blockIdx.x == 0) ? bcntE : bcntT;
    int* bb = (blockIdx.x == 0) ? bktbaseE : bktbaseT;
    int tid = threadIdx.x, lane = tid & 63, w = tid >> 6;
    __shared__ int wsum[16];
    int v = 0;
    if (tid < NBK) {
        #pragma unroll
        for (int s = 0; s < 8; ++s) v += min(bcnt[tid * 8 + s], CAPS);
    }
    int incl = v;
    #pragma unroll
    for (int s = 1; s < 64; s <<= 1) {
        int t = __shfl_up(incl, (unsigned)s, 64);
        if (lane >= s) incl += t;
    }
    if (lane == 63) wsum[w] = incl;
    __syncthreads();
    int wexcl = 0;
    for (int j = 0; j < w; ++j) wexcl += wsum[j];
    if (tid < NBK) bb[tid] = wexcl + incl - v;
}

__global__ __launch_bounds__(256) void k_place(const int* __restrict__ bcntE, const unsigned int* __restrict__ ebkt,
                                               const int* __restrict__ erow, const float* __restrict__ dist,
                                               const int* __restrict__ bktbaseE, int* __restrict__ rowptrE,
                                               int* __restrict__ slist, float* __restrict__ distS,
                                               const int* __restrict__ bcntT, const unsigned int* __restrict__ tbkt,
                                               const float* __restrict__ dist_trip, const float* __restrict__ angle,
                                               const int* __restrict__ bktbaseT, int* __restrict__ rowptrT,
                                               float2* __restrict__ tpay) {
    int b = blockIdx.x;
    bool isE = b < NBK;
    if (!isE) b -= NBK;
    int tid = threadIdx.x;
    __shared__ int ccnt[64];
    __shared__ int cbase[64];
    __shared__ int nb[8];
    if (tid < 64) ccnt[tid] = 0;
    const int* bcnt = isE ? bcntE : bcntT;
    const unsigned int* bkt = isE ? ebkt : tbkt;
    if (tid < 8) nb[tid] = min(bcnt[b * 8 + tid], CAPS);
    __syncthreads();
    for (int s = 0; s < 8; ++s) {
        int n = nb[s];
        const unsigned int* src = bkt + (size_t)(b * 8 + s) * CAPS;
        for (int i = tid; i < n; i += 256) atomicAdd(&ccnt[src[i] & 63u], 1);
    }
    __syncthreads();
    if (tid < 64) {
        int v = ccnt[tid];
        int incl = v;
        #pragma unroll
        for (int s = 1; s < 64; s <<= 1) {
            int t = __shfl_up(incl, (unsigned)s, 64);
            if (tid >= s) incl += t;
        }
        int base = (isE ? bktbaseE : bktbaseT)[b];
        int excl = base + incl - v;
        cbase[tid] = excl;
        int col = b * 64 + tid;
        int* rp = isE ? rowptrE : rowptrT;
        if (col <= N_) rp[col] = excl;
        ccnt[tid] = 0;
    }
    __syncthreads();
    for (int s = 0; s < 8; ++s) {
        int n = nb[s];
        const unsigned int* src = bkt + (size_t)(b * 8 + s) * CAPS;
        for (int i = tid; i < n; i += 256) {
            unsigned int rec = src[i];
            int c = (int)(rec & 63u);
            int e = (int)(rec >> 6);
            int off = atomicAdd(&ccnt[c], 1);
            int pos = cbase[c] + off;
            if (isE) {
                slist[pos] = erow[e];
                distS[pos] = dist[e];
            } else {
                tpay[pos] = make_float2(dist_trip[e], angle[e]);
            }
        }
    }
}

// ================= weight prep =================
__global__ __launch_bounds__(256) void k_wprep(const float* __restrict__ emb_w2, const float* __restrict__ iw_down,
                                               const float* __restrict__ iw_t1, const float* __restrict__ iw_t2,
                                               const float* __restrict__ iw_up, const float* __restrict__ ow0,
                                               const float* __restrict__ ow1, unsigned short* __restrict__ Wt) {
    int mat = blockIdx.x >> 3;
    int part = blockIdx.x & 7;
    const float* src;
    if (mat == 0) src = emb_w2;
    else if (mat < 5) src = iw_down + (size_t)(mat - 1) * 16384;
    else if (mat < 9) src = iw_t1 + (size_t)(mat - 5) * 16384;
    else if (mat < 13) src = iw_t2 + (size_t)(mat - 9) * 16384;
    else if (mat < 17) src = iw_up + (size_t)(mat - 13) * 16384;
    else if (mat < 22) src = ow0 + (size_t)(mat - 17) * 16384;
    else src = ow1 + (size_t)(mat - 22) * 16384;
    unsigned short* dst = Wt + (size_t)mat * 16384;
    int base = part * 2048;
    for (int i = base + threadIdx.x; i < base + 2048; i += 256) {
        int k = i >> 7, n = i & 127;
        dst[n * 128 + k] = f2bf(src[i]);
    }
}

// ================= merged geom + basis (both edge/triplet elementwise) =================
__global__ __launch_bounds__(256) void k_geomb(const float* __restrict__ distS,
                                               const float* __restrict__ freq, const float* __restrict__ iw_rbf1,
                                               float* __restrict__ rbfS, __half* __restrict__ s8all,
                                               const float2* __restrict__ tpay, const float* __restrict__ sfreq,
                                               __half* __restrict__ basis) {
    __shared__ float W1s[4][48];
    int tid = threadIdx.x;
    if (blockIdx.x < EG) {
        if (tid < 192) W1s[tid / 48][tid % 48] = iw_rbf1[tid];
        __syncthreads();
        int p = blockIdx.x * 256 + tid;
        if (p >= E_) return;
        float d = distS[p] * 0.2f;
        float d2 = d * d, d4 = d2 * d2, d5 = d4 * d;
        float env = __fdividef(1.0f, d) - 28.0f * d5 + 48.0f * d5 * d - 21.0f * d5 * d2;
        float rb[6];
        #pragma unroll
        for (int r = 0; r < 6; ++r) {
            rb[r] = env * __sinf(freq[r] * d);
            rbfS[(size_t)p * 6 + r] = rb[r];
        }
        #pragma unroll
        for (int b = 0; b < 4; ++b) {
            __half out[8];
            #pragma unroll
            for (int k = 0; k < 8; ++k) {
                float u = 0.f;
                #pragma unroll
                for (int r = 0; r < 6; ++r) u += rb[r] * W1s[b][r * 8 + k];
                out[k] = __float2half(siluf(u));
            }
            *(uint4*)&s8all[((size_t)b * E_ + p) * 8] = *(uint4*)out;
        }
    } else {
        int t = (blockIdx.x - EG) * 256 + tid;
        if (t >= T_) return;
        float2 da = tpay[t];
        float d = da.x * 0.2f;
        float a = da.y;
        float d2 = d * d, d4 = d2 * d2, d5 = d4 * d;
        float env = __fdividef(1.0f, d) - 28.0f * d5 + 48.0f * d5 * d - 21.0f * d5 * d2;
        float rb[6];
        #pragma unroll
        for (int r = 0; r < 6; ++r) rb[r] = env * __sinf(sfreq[r] * d);
        float sph[4];
        sph[0] = 1.0f; sph[1] = a; sph[2] = 1.5f * a * a - 0.5f; sph[3] = 2.5f * a * a * a - 1.5f * a;
        __half out[24];
        #pragma unroll
        for (int s = 0; s < 4; ++s)
            #pragma unroll
            for (int r = 0; r < 6; ++r) out[s * 6 + r] = __float2half(sph[s] * rb[r]);
        uint4* dst = (uint4*)(basis + (size_t)t * 24);
        dst[0] = ((uint4*)out)[0];
        dst[1] = ((uint4*)out)[1];
        dst[2] = ((uint4*)out)[2];
    }
}

// ================= merged init_x + embS (independent; 128 threads) =================
__global__ __launch_bounds__(128) void k_embSix(const float* __restrict__ atab, const int* __restrict__ z,
                                                unsigned short* __restrict__ xh,
                                                const int* __restrict__ rowptr, const float* __restrict__ rbfS,
                                                const float* __restrict__ w1, const float* __restrict__ b1,
                                                unsigned short* __restrict__ SSh) {
    int tid = threadIdx.x;
    if (blockIdx.x < NIX) {
        int t = blockIdx.x * 128 + tid;
        if (t >= N_ * 16) return;
        int node = t >> 4, q = t & 15;
        const float4* a4 = (const float4*)atab;
        float4 v0 = a4[(size_t)z[node] * 32 + q * 2];
        float4 v1 = a4[(size_t)z[node] * 32 + q * 2 + 1];
        uint4 pk;
        pk.x = f2bf2(v0.x, v0.y);
        pk.y = f2bf2(v0.z, v0.w);
        pk.z = f2bf2(v1.x, v1.y);
        pk.w = f2bf2(v1.z, v1.w);
        ((uint4*)xh)[t] = pk;
    } else {
        int node = (blockIdx.x - NIX) * 2 + (tid >> 6);
        int lane = tid & 63;
        if (node >= N_) return;
        int c = lane * 2;
        float wc0[6], wc1[6];
        #pragma unroll
        for (int r = 0; r < 6; ++r) { wc0[r] = w1[r * 128 + c]; wc1[r] = w1[r * 128 + c + 1]; }
        float bb0 = b1[c], bb1 = b1[c + 1];
        float a0 = 0.f, a1 = 0.f;
        int p0 = rowptr[node], p1 = rowptr[node + 1];
        int p = p0;
        for (; p + 4 <= p1; p += 4) {
            float2 rb[4][3];
            #pragma unroll
            for (int u = 0; u < 4; ++u) {
                const float2* r2 = (const float2*)&rbfS[(size_t)(p + u) * 6];
                rb[u][0] = r2[0]; rb[u][1] = r2[1]; rb[u][2] = r2[2];
            }
            #pragma unroll
            for (int u = 0; u < 4; ++u) {
                float u0 = bb0 + rb[u][0].x * wc0[0] + rb[u][0].y * wc0[1] + rb[u][1].x * wc0[2] +
                           rb[u][1].y * wc0[3] + rb[u][2].x * wc0[4] + rb[u][2].y * wc0[5];
                float u1 = bb1 + rb[u][0].x * wc1[0] + rb[u][0].y * wc1[1] + rb[u][1].x * wc1[2] +
                           rb[u][1].y * wc1[3] + rb[u][2].x * wc1[4] + rb[u][2].y * wc1[5];
                a0 += siluf(u0);
                a1 += siluf(u1);
            }
        }
        for (; p < p1; ++p) {
            const float2* r2 = (const float2*)&rbfS[(size_t)p * 6];
            float2 ra = r2[0], rbx = r2[1], rc = r2[2];
            float u0 = bb0 + ra.x * wc0[0] + ra.y * wc0[1] + rbx.x * wc0[2] + rbx.y * wc0[3] + rc.x * wc0[4] + rc.y * wc0[5];
            float u1 = bb1 + ra.x * wc1[0] + ra.y * wc1[1] + rbx.x * wc1[2] + rbx.y * wc1[3] + rc.x * wc1[4] + rc.y * wc1[5];
            a0 += siluf(u0);
            a1 += siluf(u1);
        }
        *(unsigned int*)&SSh[(size_t)node * 128 + c] = f2bf2(a0, a1);
    }
}

// ================= device bodies for fused main-loop kernels =================

// --- embedding GEMM body (BIAS=deg-scaled, ACC into xh bf16) ---
__device__ __forceinline__ void body_gemm(int bid, const unsigned short* Ap, const unsigned short* Wt,
                                          const float* bias, const int* rp, unsigned short* Ch, int M) {
    int tid = threadIdx.x;
    int wave = tid >> 6, lane = tid & 63;
    int m15 = lane & 15, quad = lane >> 4;
    int row0 = bid * 32 + wave * 16;
    int arow = row0 + m15;
    if (arow > M - 1) arow = M - 1;

    f32x4 acc[8];
    #pragma unroll
    for (int nt = 0; nt < 8; ++nt) acc[nt] = (f32x4){0.f, 0.f, 0.f, 0.f};
    #pragma unroll
    for (int kt = 0; kt < 4; ++kt) {
        int ks = kt * 32 + quad * 8;
        bf16x8 av = *(const bf16x8*)(Ap + (size_t)arow * 128 + ks);
        #pragma unroll
        for (int nt = 0; nt < 8; ++nt) {
            bf16x8 bf = *(const bf16x8*)(Wt + (size_t)(nt * 16 + m15) * 128 + ks);
            acc[nt] = __builtin_amdgcn_mfma_f32_16x16x32_bf16(av, bf, acc[nt], 0, 0, 0);
        }
    }
    #pragma unroll
    for (int nt = 0; nt < 8; ++nt) {
        int col = nt * 16 + m15;
        float bc = bias[col];
        #pragma unroll
        for (int reg = 0; reg < 4; ++reg) {
            int row = row0 + quad * 4 + reg;
            if (row < M) {
                float v = acc[nt][reg] + bc * (float)(rp[row + 1] - rp[row]);
                v += bf2f(Ch[(size_t)row * 128 + col]);
                Ch[(size_t)row * 128 + col] = f2bf(v);
            }
        }
    }
}

// --- sv4 body (128 threads / 4 nodes) ---
__device__ __forceinline__ void body_sv4(int bid, const int* rowptrT, const __half* basis,
                                         const float* iw_sbf1, float* SV4, int n) {
    int tid = threadIdx.x;
    int wave = tid >> 6, lane = tid & 63;
    int node = bid * 4 + wave * 2 + (lane >> 5);
    int sub = lane & 31;
    int blk = sub >> 3, k = sub & 7;
    if (node >= n) return;
    const float* W1 = iw_sbf1 + blk * 192;
    f16x2 w[12];
    #pragma unroll
    for (int j = 0; j < 12; ++j) {
        f16x2 t;
        t.x = (_Float16)W1[(2 * j) * 8 + k];
        t.y = (_Float16)W1[(2 * j + 1) * 8 + k];
        w[j] = t;
    }
    float acc = 0.f;
    int p0 = rowptrT[node], p1 = rowptrT[node + 1];
    for (int p = p0; p < p1; ++p) {
        union { uint4 q[3]; f16x2 h[12]; } bs;
        const uint4* bp = (const uint4*)(basis + (size_t)p * 24);
        bs.q[0] = bp[0]; bs.q[1] = bp[1]; bs.q[2] = bp[2];
        float u = 0.f;
        #pragma unroll
        for (int j = 0; j < 12; ++j) u = fdot2f(bs.h[j], w[j], u);
        acc += siluf(u);
    }
    SV4[((size_t)blk * n + node) * 8 + k] = acc;
}

// --- out_gather body (128 threads / 2 nodes) ---
__device__ __forceinline__ void body_gather(int node0, const int* rowptr, const int* slist,
                                            const float* rbfS, const unsigned short* xh,
                                            const float* wrbf, unsigned short* hB, int n) {
    int tid = threadIdx.x;
    int node = node0 + (tid >> 6);
    int lane = tid & 63;
    if (node >= n) return;
    int c = lane * 2;
    float wc0[6], wc1[6];
    #pragma unroll
    for (int r = 0; r < 6; ++r) { wc0[r] = wrbf[r * 128 + c]; wc1[r] = wrbf[r * 128 + c + 1]; }
    float a0 = 0.f, a1 = 0.f;
    int p0 = rowptr[node], p1 = rowptr[node + 1];
    int p = p0;
    for (; p + 4 <= p1; p += 4) {
        int s0 = slist[p], s1 = slist[p + 1], s2 = slist[p + 2], s3 = slist[p + 3];
        float2 rb[4][3];
        #pragma unroll
        for (int u = 0; u < 4; ++u) {
            const float2* r2 = (const float2*)&rbfS[(size_t)(p + u) * 6];
            rb[u][0] = r2[0]; rb[u][1] = r2[1]; rb[u][2] = r2[2];
        }
        unsigned int xv0 = *(const unsigned int*)&xh[(size_t)s0 * 128 + c];
        unsigned int xv1 = *(const unsigned int*)&xh[(size_t)s1 * 128 + c];
        unsigned int xv2 = *(const unsigned int*)&xh[(size_t)s2 * 128 + c];
        unsigned int xv3 = *(const unsigned int*)&xh[(size_t)s3 * 128 + c];
        #pragma unroll
        for (int u = 0; u < 4; ++u) {
            float e0 = rb[u][0].x * wc0[0] + rb[u][0].y * wc0[1] + rb[u][1].x * wc0[2] +
                       rb[u][1].y * wc0[3] + rb[u][2].x * wc0[4] + rb[u][2].y * wc0[5];
            float e1 = rb[u][0].x * wc1[0] + rb[u][0].y * wc1[1] + rb[u][1].x * wc1[2] +
                       rb[u][1].y * wc1[3] + rb[u][2].x * wc1[4] + rb[u][2].y * wc1[5];
            float2 xf = bf2x2((u == 0) ? xv0 : (u == 1) ? xv1 : (u == 2) ? xv2 : xv3);
            a0 += xf.x * e0;
            a1 += xf.y * e1;
        }
    }
    for (; p < p1; ++p) {
        int src = slist[p];
        const float2* r2 = (const float2*)&rbfS[(size_t)p * 6];
        float2 ra = r2[0], rbx = r2[1], rc = r2[2];
        float e0 = ra.x * wc0[0] + ra.y * wc0[1] + rbx.x * wc0[2] + rbx.y * wc0[3] + rc.x * wc0[4] + rc.y * wc0[5];
        float e1 = ra.x * wc1[0] + ra.y * wc1[1] + rbx.x * wc1[2] + rbx.y * wc1[3] + rc.x * wc1[4] + rc.y * wc1[5];
        float2 xf = bf2x2(*(const unsigned int*)&xh[(size_t)src * 128 + c]);
        a0 += xf.x * e0;
        a1 += xf.y * e1;
    }
    *(unsigned int*)&hB[(size_t)node * 128 + c] = f2bf2(a0, a1);
}

// --- block_mlp body (128 threads / 32 rows; bf16 t-tile reuses GEMM scratch) ---
__device__ __forceinline__ void body_block_mlp(int bid, unsigned short* smh,
                                               const unsigned short* xh,
                                               const unsigned short* Wd, const float* bd,
                                               const unsigned short* Wt1,
                                               const unsigned short* Wt2, const float* bt2,
                                               const unsigned short* Wup, const float* bup,
                                               const float* SV, const float* W2,
                                               float* extraP, unsigned short* xuph, int M) {
    int tid = threadIdx.x;
    int wave = tid >> 6, lane = tid & 63;
    int m15 = lane & 15, quad = lane >> 4;
    int row0 = bid * 32 + wave * 16;
    int arow = row0 + m15;
    if (arow > M - 1) arow = M - 1;
    unsigned short* L = smh + wave * (16 * 136);

    f32x4 accD[8], accU[8];
    #pragma unroll
    for (int nt = 0; nt < 8; ++nt) { accD[nt] = (f32x4){0.f, 0.f, 0.f, 0.f}; accU[nt] = (f32x4){0.f, 0.f, 0.f, 0.f}; }
    #pragma unroll
    for (int kt = 0; kt < 4; ++kt) {
        int ks = kt * 32 + quad * 8;
        bf16x8 av = *(const bf16x8*)(xh + (size_t)arow * 128 + ks);
        #pragma unroll
        for (int nt = 0; nt < 8; ++nt) {
            bf16x8 bd_ = *(const bf16x8*)(Wd + (size_t)(nt * 16 + m15) * 128 + ks);
            accD[nt] = __builtin_amdgcn_mfma_f32_16x16x32_bf16(av, bd_, accD[nt], 0, 0, 0);
            bf16x8 bu_ = *(const bf16x8*)(Wup + (size_t)(nt * 16 + m15) * 128 + ks);
            accU[nt] = __builtin_amdgcn_mfma_f32_16x16x32_bf16(av, bu_, accU[nt], 0, 0, 0);
        }
    }
    #pragma unroll
    for (int nt = 0; nt < 8; ++nt) {
        int col = nt * 16 + m15;
        float bcu = bup[col], bcd = bd[col];
        #pragma unroll
        for (int reg = 0; reg < 4; ++reg) {
            int row = row0 + quad * 4 + reg;
            if (row < M) xuph[(size_t)row * 128 + col] = f2bf(accU[nt][reg] + bcu);
            L[(quad * 4 + reg) * 136 + col] = f2bf(accD[nt][reg] + bcd);
        }
    }
    __syncthreads();

    #pragma unroll
    for (int nt = 0; nt < 8; ++nt) accD[nt] = (f32x4){0.f, 0.f, 0.f, 0.f};
    #pragma unroll
    for (int kt = 0; kt < 4; ++kt) {
        int ks = kt * 32 + quad * 8;
        bf16x8 av = *(const bf16x8*)(L + m15 * 136 + ks);
        #pragma unroll
        for (int nt = 0; nt < 8; ++nt) {
            bf16x8 bf = *(const bf16x8*)(Wt1 + (size_t)(nt * 16 + m15) * 128 + ks);
            accD[nt] = __builtin_amdgcn_mfma_f32_16x16x32_bf16(av, bf, accD[nt], 0, 0, 0);
        }
    }
    __syncthreads();
    #pragma unroll
    for (int nt = 0; nt < 8; ++nt) {
        int col = nt * 16 + m15;
        #pragma unroll
        for (int reg = 0; reg < 4; ++reg)
            L[(quad * 4 + reg) * 136 + col] = f2bf(siluf(accD[nt][reg]));
    }
    __syncthreads();

    #pragma unroll
    for (int nt = 0; nt < 8; ++nt) accD[nt] = (f32x4){0.f, 0.f, 0.f, 0.f};
    #pragma unroll
    for (int kt = 0; kt < 4; ++kt) {
        int ks = kt * 32 + quad * 8;
        bf16x8 av = *(const bf16x8*)(L + m15 * 136 + ks);
        #pragma unroll
        for (int nt = 0; nt < 8; ++nt) {
            bf16x8 bf = *(const bf16x8*)(Wt2 + (size_t)(nt * 16 + m15) * 128 + ks);
            accD[nt] = __builtin_amdgcn_mfma_f32_16x16x32_bf16(av, bf, accD[nt], 0, 0, 0);
        }
    }
    __syncthreads();
    // t-tile (bf16) reuses the full 32x136 GEMM scratch; rows = wave*16+quad*4+reg
    #pragma unroll
    for (int nt = 0; nt < 8; ++nt) {
        int col = nt * 16 + m15;
        float bc = bt2[col];
        #pragma unroll
        for (int reg = 0; reg < 4; ++reg)
            smh[(wave * 16 + quad * 4 + reg) * 136 + col] = f2bf(accD[nt][reg] + bc);
    }
    __syncthreads();

    int col = tid;  // 0..127
    float acc8[8];
    #pragma unroll
    for (int k = 0; k < 8; ++k) acc8[k] = 0.f;
    int rmax = M - bid * 32;
    if (rmax > 32) rmax = 32;
    for (int rr = 0; rr < rmax; ++rr) {
        float t = bf2f(smh[rr * 136 + col]);
        const float4* sv4 = (const float4*)&SV[(size_t)(bid * 32 + rr) * 8];
        float4 s0 = sv4[0], s1 = sv4[1];
        acc8[0] += t * s0.x; acc8[1] += t * s0.y; acc8[2] += t * s0.z; acc8[3] += t * s0.w;
        acc8[4] += t * s1.x; acc8[5] += t * s1.y; acc8[6] += t * s1.z; acc8[7] += t * s1.w;
    }
    float e = 0.f;
    #pragma unroll
    for (int k = 0; k < 8; ++k) e += acc8[k] * W2[k * 128 + col];
    atomicAdd(&extraP[(bid & (XSLOT - 1)) * 128 + col], e);
}

// --- out_mlp body (128 threads / 32 rows) ---
template <int PACC>
__device__ __forceinline__ void body_out_mlp(int bid, unsigned short* smh,
                                             const unsigned short* hB,
                                             const unsigned short* W0t, const float* b0,
                                             const unsigned short* W1t, const float* b1,
                                             const float* w2col, const float* ob2p,
                                             float* Pout, int M) {
    int tid = threadIdx.x;
    int wave = tid >> 6, lane = tid & 63;
    int m15 = lane & 15, quad = lane >> 4;
    int row0 = bid * 32 + wave * 16;
    int arow = row0 + m15;
    if (arow > M - 1) arow = M - 1;
    unsigned short* L = smh + wave * (16 * 136);

    f32x4 acc[8];
    #pragma unroll
    for (int nt = 0; nt < 8; ++nt) acc[nt] = (f32x4){0.f, 0.f, 0.f, 0.f};
    #pragma unroll
    for (int kt = 0; kt < 4; ++kt) {
        int ks = kt * 32 + quad * 8;
        bf16x8 av = *(const bf16x8*)(hB + (size_t)arow * 128 + ks);
        #pragma unroll
        for (int nt = 0; nt < 8; ++nt) {
            bf16x8 bf = *(const bf16x8*)(W0t + (size_t)(nt * 16 + m15) * 128 + ks);
            acc[nt] = __builtin_amdgcn_mfma_f32_16x16x32_bf16(av, bf, acc[nt], 0, 0, 0);
        }
    }
    #pragma unroll
    for (int nt = 0; nt < 8; ++nt) {
        int col = nt * 16 + m15;
        float bc = b0[col];
        #pragma unroll
        for (int reg = 0; reg < 4; ++reg)
            L[(quad * 4 + reg) * 136 + col] = f2bf(siluf(acc[nt][reg] + bc));
    }
    __syncthreads();

    #pragma unroll
    for (int nt = 0; nt < 8; ++nt) acc[nt] = (f32x4){0.f, 0.f, 0.f, 0.f};
    #pragma unroll
    for (int kt = 0; kt < 4; ++kt) {
        int ks = kt * 32 + quad * 8;
        bf16x8 av = *(const bf16x8*)(L + m15 * 136 + ks);
        #pragma unroll
        for (int nt = 0; nt < 8; ++nt) {
            bf16x8 bf = *(const bf16x8*)(W1t + (size_t)(nt * 16 + m15) * 128 + ks);
            acc[nt] = __builtin_amdgcn_mfma_f32_16x16x32_bf16(av, bf, acc[nt], 0, 0, 0);
        }
    }
    float w2c[8], pp[4];
    #pragma unroll
    for (int nt = 0; nt < 8; ++nt) w2c[nt] = w2col[nt * 16 + m15];
    #pragma unroll
    for (int reg = 0; reg < 4; ++reg) pp[reg] = 0.f;
    #pragma unroll
    for (int nt = 0; nt < 8; ++nt) {
        float bc = b1[nt * 16 + m15];
        #pragma unroll
        for (int reg = 0; reg < 4; ++reg)
            pp[reg] += siluf(acc[nt][reg] + bc) * w2c[nt];
    }
    #pragma unroll
    for (int reg = 0; reg < 4; ++reg) {
        float s = pp[reg];
        s += __shfl_xor(s, 1, 64);
        s += __shfl_xor(s, 2, 64);
        s += __shfl_xor(s, 4, 64);
        s += __shfl_xor(s, 8, 64);
        if (m15 == 0) {
            int row = row0 + quad * 4 + reg;
            if (row < M) {
                float r = s + ob2p[0];
                if (PACC == 2) r += Pout[row];
                Pout[row] = r;
            }
        }
    }
}

// --- interact body (128 threads / 2 nodes; exs presum in small LDS) ---
__device__ __forceinline__ void body_interact(int node0, float* exs,
                                              const int* rowptr, const int* slist,
                                              const __half* s8, const float* W2,
                                              const float* extraP,
                                              const unsigned short* xuph,
                                              unsigned short* xh, int n) {
    int tid = threadIdx.x;
    {
        float s = 0.f;
        #pragma unroll
        for (int q = 0; q < XSLOT; ++q) s += extraP[q * 128 + tid];
        exs[tid] = s;
    }
    __syncthreads();
    int node = node0 + (tid >> 6);
    int lane = tid & 63;
    if (node >= n) return;
    int c = lane * 2;
    f16x2 w2a[4], w2b[4];
    #pragma unroll
    for (int j = 0; j < 4; ++j) {
        f16x2 wa, wb;
        wa.x = (_Float16)W2[(2 * j) * 128 + c];
        wa.y = (_Float16)W2[(2 * j + 1) * 128 + c];
        wb.x = (_Float16)W2[(2 * j) * 128 + c + 1];
        wb.y = (_Float16)W2[(2 * j + 1) * 128 + c + 1];
        w2a[j] = wa;
        w2b[j] = wb;
    }
    int p0 = rowptr[node], p1 = rowptr[node + 1];
    float cntf = (float)(p1 - p0);
    float a0 = cntf * exs[c], a1 = cntf * exs[c + 1];
    int p = p0;
    for (; p + 4 <= p1; p += 4) {
        int s0 = slist[p], s1 = slist[p + 1], s2 = slist[p + 2], s3 = slist[p + 3];
        uint4 sv[4];
        #pragma unroll
        for (int u = 0; u < 4; ++u) sv[u] = *(const uint4*)(s8 + (size_t)(p + u) * 8);
        unsigned int xv0 = *(const unsigned int*)&xuph[(size_t)s0 * 128 + c];
        unsigned int xv1 = *(const unsigned int*)&xuph[(size_t)s1 * 128 + c];
        unsigned int xv2 = *(const unsigned int*)&xuph[(size_t)s2 * 128 + c];
        unsigned int xv3 = *(const unsigned int*)&xuph[(size_t)s3 * 128 + c];
        #pragma unroll
        for (int u = 0; u < 4; ++u) {
            union { uint4 q; f16x2 h[4]; } s;
            s.q = sv[u];
            float e0 = fdot2f(s.h[0], w2a[0], 0.f);
            e0 = fdot2f(s.h[1], w2a[1], e0);
            e0 = fdot2f(s.h[2], w2a[2], e0);
            e0 = fdot2f(s.h[3], w2a[3], e0);
            float e1 = fdot2f(s.h[0], w2b[0], 0.f);
            e1 = fdot2f(s.h[1], w2b[1], e1);
            e1 = fdot2f(s.h[2], w2b[2], e1);
            e1 = fdot2f(s.h[3], w2b[3], e1);
            float2 xf = bf2x2((u == 0) ? xv0 : (u == 1) ? xv1 : (u == 2) ? xv2 : xv3);
            a0 += xf.x * e0;
            a1 += xf.y * e1;
        }
    }
    for (; p < p1; ++p) {
        int src = slist[p];
        float2 xf = bf2x2(*(const unsigned int*)&xuph[(size_t)src * 128 + c]);
        union { uint4 q; f16x2 h[4]; } s;
        s.q = *(const uint4*)(s8 + (size_t)p * 8);
        float e0 = fdot2f(s.h[0], w2a[0], 0.f);
        e0 = fdot2f(s.h[1], w2a[1], e0);
        e0 = fdot2f(s.h[2], w2a[2], e0);
        e0 = fdot2f(s.h[3], w2a[3], e0);
        float e1 = fdot2f(s.h[0], w2b[0], 0.f);
        e1 = fdot2f(s.h[1], w2b[1], e1);
        e1 = fdot2f(s.h[2], w2b[2], e1);
        e1 = fdot2f(s.h[3], w2b[3], e1);
        a0 += xf.x * e0;
        a1 += xf.y * e1;
    }
    unsigned int cur = *(unsigned int*)&xh[(size_t)node * 128 + c];
    float2 xc = bf2x2(cur);
    *(unsigned int*)&xh[(size_t)node * 128 + c] = f2bf2(xc.x + a0, xc.y + a1);
}

// ================= fused kernels =================

// embedding GEMM + sv4 (independent)
__global__ __launch_bounds__(128) void k_gemmsv(const unsigned short* __restrict__ Ap,
                                                const unsigned short* __restrict__ Wt,
                                                const float* __restrict__ bias, const int* __restrict__ rp,
                                                unsigned short* __restrict__ Ch,
                                                const int* __restrict__ rowptrT, const __half* __restrict__ basis,
                                                const float* __restrict__ iw_sbf1, float* __restrict__ SV4) {
    if (blockIdx.x < GEMMG2)
        body_gemm(blockIdx.x, Ap, Wt, bias, rp, Ch, N_);
    else
        body_sv4(blockIdx.x - GEMMG2, rowptrT, basis, iw_sbf1, SV4, N_);
}

// block_mlp(b) + out_gather(b): both only READ xh
__global__ __launch_bounds__(128) void k_fuse_gb(const unsigned short* __restrict__ xh,
                                                 const unsigned short* __restrict__ Wd, const float* __restrict__ bd,
                                                 const unsigned short* __restrict__ Wt1,
                                                 const unsigned short* __restrict__ Wt2, const float* __restrict__ bt2,
                                                 const unsigned short* __restrict__ Wup, const float* __restrict__ bup,
                                                 const float* __restrict__ SV, const float* __restrict__ W2,
                                                 float* __restrict__ extraP, unsigned short* __restrict__ xuph,
                                                 const int* __restrict__ rowptr, const int* __restrict__ slist,
                                                 const float* __restrict__ rbfS, const float* __restrict__ wrbf,
                                                 unsigned short* __restrict__ hB) {
    __shared__ unsigned short smh[2 * 16 * 136];
    if (blockIdx.x < GEMMG2)
        body_block_mlp(blockIdx.x, smh, xh, Wd, bd, Wt1, Wt2, bt2, Wup, bup, SV, W2, extraP, xuph, N_);
    else
        body_gather((blockIdx.x - GEMMG2) * 2, rowptr, slist, rbfS, xh, wrbf, hB, N_);
}

// out_mlp(b) + interact(b): disjoint (hB->P vs xh update)
template <int PACC>
__global__ __launch_bounds__(128) void k_fuse_mi(const unsigned short* __restrict__ hB,
                                                 const unsigned short* __restrict__ W0t, const float* __restrict__ b0,
                                                 const unsigned short* __restrict__ W1t, const float* __restrict__ b1,
                                                 const float* __restrict__ w2col, const float* __restrict__ ob2p,
                                                 float* __restrict__ Pout,
                                                 const int* __restrict__ rowptr, const int* __restrict__ slist,
                                                 const __half* __restrict__ s8, const float* __restrict__ W2,
                                                 const float* __restrict__ extraP,
                                                 const unsigned short* __restrict__ xuph,
                                                 unsigned short* __restrict__ xh) {
    __shared__ unsigned short smh[2 * 16 * 136];
    if (blockIdx.x < GEMMG2)
        body_out_mlp<PACC>(blockIdx.x, smh, hB, W0t, b0, W1t, b1, w2col, ob2p, Pout, N_);
    else
        body_interact((blockIdx.x - GEMMG2) * 2, (float*)smh, rowptr, slist, s8, W2, extraP, xuph, xh, N_);
}

// standalone wrappers for the final out_block
__global__ __launch_bounds__(128) void k_gather1(const int* __restrict__ rowptr, const int* __restrict__ slist,
                                                 const float* __restrict__ rbfS, const unsigned short* __restrict__ xh,
                                                 const float* __restrict__ wrbf, unsigned short* __restrict__ hB) {
    body_gather(blockIdx.x * 2, rowptr, slist, rbfS, xh, wrbf, hB, N_);
}
__global__ __launch_bounds__(128) void k_mlp1(const unsigned short* __restrict__ hB,
                                              const unsigned short* __restrict__ W0t, const float* __restrict__ b0,
                                              const unsigned short* __restrict__ W1t, const float* __restrict__ b1,
                                              const float* __restrict__ w2col, const float* __restrict__ ob2p,
                                              float* __restrict__ Pout) {
    __shared__ unsigned short smh[2 * 16 * 136];
    body_out_mlp<2>(blockIdx.x, smh, hB, W0t, b0, W1t, b1, w2col, ob2p, Pout, N_);
}

// ================= pooling =================
__global__ __launch_bounds__(256) void k_pool(const float* __restrict__ P, const int* __restrict__ batch,
                                              float* __restrict__ pool, float* __restrict__ cnt, int n) {
    int i = blockIdx.x * 256 + threadIdx.x;
    int lane = threadIdx.x & 63;
    int b = (i < n) ? batch[i] : -1;
    float p = (i < n) ? P[i] : 0.f;
    int b0 = __shfl(b, 0, 64);
    int b63 = __shfl(b, 63, 64);
    if (b0 == b63 && b0 >= 0) {
        float s = p;
        #pragma unroll
        for (int off = 32; off > 0; off >>= 1) s += __shfl_xor(s, off, 64);
        if (lane == 0) {
            atomicAdd(&pool[b0], s);
            atomicAdd(&cnt[b0], 64.0f);
        }
    } else {
        if (i < n) {
            atomicAdd(&pool[b], p);
            atomicAdd(&cnt[b], 1.0f);
        }
    }
}

__global__ __launch_bounds__(64) void k_final(const float* __restrict__ pool, const float* __restrict__ cnt,
                                              float* __restrict__ out) {
    int g = threadIdx.x;
    if (g < G_) out[g] = __fdividef(pool[g], fmaxf(cnt[g], 1.0f));
}

extern "C" void kernel_launch(void* const* d_in, const int* in_sizes, int n_in,
                              void* d_out, int out_size, void* d_ws, size_t ws_size,
                              hipStream_t stream) {
    (void)in_sizes; (void)n_in; (void)out_size; (void)ws_size;
    const int* z = (const int*)d_in[0];
    const float* dist = (const float*)d_in[1];
    const float* dist_trip = (const float*)d_in[2];
    const float* angle = (const float*)d_in[3];
    const int* edge_index = (const int*)d_in[4];
    const int* triplets = (const int*)d_in[5];
    const int* batch = (const int*)d_in[6];
    const float* atom_table = (const float*)d_in[7];
    const float* rbf_freq = (const float*)d_in[8];
    const float* sbf_freq = (const float*)d_in[9];
    const float* emb_w1 = (const float*)d_in[10];
    const float* emb_b1 = (const float*)d_in[11];
    const float* emb_w2 = (const float*)d_in[12];
    const float* emb_b2 = (const float*)d_in[13];
    const float* iw_rbf1 = (const float*)d_in[14];
    const float* iw_rbf2 = (const float*)d_in[15];
    const float* iw_sbf1 = (const float*)d_in[16];
    const float* iw_sbf2 = (const float*)d_in[17];
    const float* iw_t1 = (const float*)d_in[18];
    const float* iw_t2 = (const float*)d_in[19];
    const float* ib_t2 = (const float*)d_in[20];
    const float* iw_up = (const float*)d_in[21];
    const float* ib_up = (const float*)d_in[22];
    const float* iw_down = (const float*)d_in[23];
    const float* ib_down = (const float*)d_in[24];
    const float* ow_rbf = (const float*)d_in[25];
    const float* ow0 = (const float*)d_in[26];
    const float* ob0 = (const float*)d_in[27];
    const float* ow1 = (const float*)d_in[28];
    const float* ob1 = (const float*)d_in[29];
    const float* ow2 = (const float*)d_in[30];
    const float* ob2 = (const float*)d_in[31];

    const int* erow = edge_index;
    const int* ecol = edge_index + E_;

    // workspace layout
    float* ws = (float*)d_ws;
    float* bufA = ws;                          // N*128 (embS bf16 out)
    float* bufB = bufA + (size_t)N_ * H_;      // N*128 (hB bf16)
    float* P = bufB + (size_t)N_ * H_;         // N
    float* rbfS = P + N_;                      // E*6 (CSR order)
    float* SV4 = rbfS + (size_t)E_ * 6;        // 4*N*8
    float* extra4 = SV4 + (size_t)4 * N_ * 8;  // 4 * XSLOT * 128
    float* pool = extra4 + 4 * XSLOT * 128;    // G
    float* cnt = pool + G_;                    // G
    int* bcntE = (int*)(cnt + G_);             // NSB
    int* bcntT = bcntE + NSB;                  // NSB
    int* bktbaseE = bcntT + NSB;               // NBK
    int* bktbaseT = bktbaseE + NBK;            // NBK
    int* rowptr = bktbaseT + NBK;              // N+1
    int* rowptrT = rowptr + N_ + 1;            // N+1
    int* slist = rowptrT + N_ + 1;             // E
    float* distS = (float*)(slist + E_);       // E
    uintptr_t tp = (uintptr_t)(distS + E_);
    tp = (tp + 7) & ~(uintptr_t)7;
    float2* tpay = (float2*)tp;                // T float2
    __half* s8all = (__half*)(tpay + T_);      // 4*E*8 halves
    __half* basis = s8all + (size_t)4 * E_ * 8;                          // T*24 halves
    unsigned short* xh = (unsigned short*)(basis + (size_t)T_ * 24);     // N*128 bf16 node state
    unsigned short* xuph = xh + (size_t)N_ * H_;                          // N*128 bf16 x_up
    unsigned short* Wt = xuph + (size_t)N_ * H_;                          // 27*16384 bf16 weights
    unsigned short* hB = (unsigned short*)bufB;

    // bucket arrays alias s8all region (written later by k_geomb) — 4B packed records
    unsigned int* ebkt = (unsigned int*)s8all;               // NSB*CAPS uint = 12.8MB
    unsigned int* tbkt = ebkt + (size_t)NSB * CAPS;          // NSB*CAPS uint = 12.8MB

    hipMemsetAsync(extra4, 0, (4 * XSLOT * 128 + 2 * G_ + 2 * NSB) * sizeof(float), stream);
    k_wprep<<<27 * 8, 256, 0, stream>>>(emb_w2, iw_down, iw_t1, iw_t2, iw_up, ow0, ow1, Wt);
    k_bucket<<<EB + TB, 256, 0, stream>>>(ecol, triplets, bcntE, ebkt, bcntT, tbkt);
    k_scanB<<<2, 1024, 0, stream>>>(bcntE, bktbaseE, bcntT, bktbaseT);
    k_place<<<2 * NBK, 256, 0, stream>>>(bcntE, ebkt, erow, dist, bktbaseE, rowptr, slist, distS,
                                         bcntT, tbkt, dist_trip, angle, bktbaseT, rowptrT, tpay);

    k_geomb<<<EG + TG, 256, 0, stream>>>(distS, rbf_freq, iw_rbf1, rbfS, s8all,
                                         tpay, sbf_freq, basis);
    k_embSix<<<NIX + NG2, 128, 0, stream>>>(atom_table, z, xh, rowptr, rbfS, emb_w1, emb_b1,
                                            (unsigned short*)bufA);
    k_gemmsv<<<GEMMG2 + SVG, 128, 0, stream>>>((unsigned short*)bufA, Wt, emb_b2, rowptr, xh,
                                               rowptrT, basis, iw_sbf1, SV4);

    for (int b = 0; b < 4; ++b) {
        // L1: block_mlp(b) || out_gather(k=b)  (both read xh)
        k_fuse_gb<<<GEMMG2 + NG2, 128, 0, stream>>>(xh,
                                                    Wt + (size_t)(1 + b) * 16384, ib_down + b * 128,
                                                    Wt + (size_t)(5 + b) * 16384,
                                                    Wt + (size_t)(9 + b) * 16384, ib_t2 + b * 128,
                                                    Wt + (size_t)(13 + b) * 16384, ib_up + b * 128,
                                                    SV4 + (size_t)b * N_ * 8,
                                                    iw_sbf2 + (size_t)b * 1024,
                                                    extra4 + (size_t)b * XSLOT * 128,
                                                    xuph,
                                                    rowptr, slist, rbfS,
                                                    ow_rbf + (size_t)b * 6 * 128, hB);
        // L2: out_mlp(k=b) || interact(b)
        if (b == 0)
            k_fuse_mi<1><<<GEMMG2 + NG2, 128, 0, stream>>>(hB,
                                                           Wt + (size_t)(17 + b) * 16384, ob0 + b * 128,
                                                           Wt + (size_t)(22 + b) * 16384, ob1 + b * 128,
                                                           ow2 + b * 128, ob2 + b, P,
                                                           rowptr, slist, s8all + (size_t)b * E_ * 8,
                                                           iw_rbf2 + (size_t)b * 1024,
                                                           extra4 + (size_t)b * XSLOT * 128,
                                                           xuph, xh);
        else
            k_fuse_mi<2><<<GEMMG2 + NG2, 128, 0, stream>>>(hB,
                                                           Wt + (size_t)(17 + b) * 16384, ob0 + b * 128,
                                                           Wt + (size_t)(22 + b) * 16384, ob1 + b * 128,
                                                           ow2 + b * 128, ob2 + b, P,
                                                           rowptr, slist, s8all + (size_t)b * E_ * 8,
                                                           iw_rbf2 + (size_t)b * 1024,
                                                           extra4 + (size_t)b * XSLOT * 128,
                                                           xuph, xh);
    }

    // final out_block (k = 4)
    k_gather1<<<NG2, 128, 0, stream>>>(rowptr, slist, rbfS, xh, ow_rbf + (size_t)4 * 6 * 128, hB);
    k_mlp1<<<GEMMG2, 128, 0, stream>>>(hB, Wt + (size_t)21 * 16384, ob0 + 4 * 128,
                                       Wt + (size_t)26 * 16384, ob1 + 4 * 128,
                                       ow2 + 4 * 128, ob2 + 4, P);

    k_pool<<<(N_ + 255) / 256, 256, 0, stream>>>(P, batch, pool, cnt, N_);
    k_final<<<1, 64, 0, stream>>>(pool, cnt, (float*)d_out);
}

// Round 5
// 1468.482 us; speedup vs baseline: 1.0440x; 1.0440x over previous
//
#include <hip/hip_runtime.h>
#include <hip/hip_fp16.h>

#define N_ 50000
#define E_ 800000
#define T_ 800000
#define G_ 64
#define H_ 128

// bucket sort geometry: 64 cols per bucket, 8 XCD-affine sub-buckets each
#define NBK 782            // ceil(N/64)
#define NSB (NBK * 8)      // 6256 sub-buckets
#define CAPS 512           // entries per sub-bucket (mean ~128)
#define CHUNK 4096         // elements per k_bucket block
#define EB ((E_ + CHUNK - 1) / CHUNK)   // 196
#define TB ((T_ + CHUNK - 1) / CHUNK)   // 196
#define XSLOT 16           // extra-reduction atomic slots

#define GEMMG2 ((N_ + 31) / 32)     // 1563 MFMA blocks (128 thr / 32 rows)
#define NG2 ((N_ + 1) / 2)          // 25000 embS blocks (128 thr / 2 nodes)
#define NG4 ((N_ + 3) / 4)          // 12500 gather blocks (256 thr / 4 nodes)
#define NIX ((N_ * 16 + 127) / 128) // 6250 init_x blocks
#define SVG ((N_ + 3) / 4)          // 12500 sv4 blocks (128 thr / 4 nodes)
#define EG ((E_ + 255) / 256)
#define TG ((T_ + 255) / 256)

typedef __attribute__((ext_vector_type(8))) short bf16x8;
typedef __attribute__((ext_vector_type(4))) float f32x4;
typedef _Float16 f16x2 __attribute__((ext_vector_type(2)));

__device__ __forceinline__ float siluf(float v) {
    return __fdividef(v, 1.0f + __expf(-v));
}

__device__ __forceinline__ unsigned short f2bf(float f) {
    unsigned int u = __float_as_uint(f);
    u += 0x7fffu + ((u >> 16) & 1u);
    return (unsigned short)(u >> 16);
}
__device__ __forceinline__ unsigned int f2bf2(float a, float b) {
    return (unsigned int)f2bf(a) | ((unsigned int)f2bf(b) << 16);
}
__device__ __forceinline__ float bf2f(unsigned short h) {
    return __uint_as_float(((unsigned int)h) << 16);
}
__device__ __forceinline__ float2 bf2x2(unsigned int p) {
    return make_float2(__uint_as_float(p << 16), __uint_as_float(p & 0xffff0000u));
}
__device__ __forceinline__ float fdot2f(f16x2 a, f16x2 b, float c) {
    return __builtin_amdgcn_fdot2(a, b, c, false);
}

// ================= CSR build =================
__global__ __launch_bounds__(256) void k_bucket(const int* __restrict__ ecol,
                                                const int* __restrict__ trip,
                                                int* bcntE, unsigned int* __restrict__ ebkt,
                                                int* bcntT, unsigned int* __restrict__ tbkt) {
    __shared__ int hist[NBK];
    __shared__ int bbase[NBK];
    int blk = blockIdx.x;
    bool isE = blk < EB;
    int ebase = (isE ? blk : blk - EB) * CHUNK;
    const int nElem = isE ? E_ : T_;
    int r = blk & 7;
    int* bcnt = isE ? bcntE : bcntT;
    unsigned int* bkt = isE ? ebkt : tbkt;
    int tid = threadIdx.x;

    for (int i = tid; i < NBK; i += 256) hist[i] = 0;
    __syncthreads();

    int cols[16];
    #pragma unroll
    for (int u = 0; u < 16; ++u) {
        int idx = ebase + u * 256 + tid;
        int c = -1;
        if (idx < nElem) c = isE ? ecol[idx] : trip[3 * idx + 1];
        cols[u] = c;
        if (c >= 0) atomicAdd(&hist[c >> 6], 1);
    }
    __syncthreads();

    for (int b = tid; b < NBK; b += 256) {
        int c = hist[b];
        bbase[b] = c ? atomicAdd(&bcnt[b * 8 + r], c) : 0;
        hist[b] = 0;
    }
    __syncthreads();

    #pragma unroll
    for (int u = 0; u < 16; ++u) {
        int c = cols[u];
        if (c >= 0) {
            int bk = c >> 6;
            int off = atomicAdd(&hist[bk], 1);
            int pos = bbase[bk] + off;
            if (pos < CAPS) {
                int idx = ebase + u * 256 + tid;
                bkt[(size_t)(bk * 8 + r) * CAPS + pos] =
                    ((unsigned int)idx << 6) | (unsigned int)(c & 63);
            }
        }
    }
}

__global__ __launch_bounds__(1024) void k_scanB(const int* __restrict__ bcntE, int* bktbaseE,
                                                const int* __restrict__ bcntT, int* bktbaseT) {
    const int* bcnt = (blockIdx.x == 0) ? bcntE : bcntT;
    int* bb = (blockIdx.x == 0) ? bktbaseE : bktbaseT;
    int tid = threadIdx.x, lane = tid & 63, w = tid >> 6;
    __shared__ int wsum[16];
    int v = 0;
    if (tid < NBK) {
        #pragma unroll
        for (int s = 0; s < 8; ++s) v += min(bcnt[tid * 8 + s], CAPS);
    }
    int incl = v;
    #pragma unroll
    for (int s = 1; s < 64; s <<= 1) {
        int t = __shfl_up(incl, (unsigned)s, 64);
        if (lane >= s) incl += t;
    }
    if (lane == 63) wsum[w] = incl;
    __syncthreads();
    int wexcl = 0;
    for (int j = 0; j < w; ++j) wexcl += wsum[j];
    if (tid < NBK) bb[tid] = wexcl + incl - v;
}

__global__ __launch_bounds__(256) void k_place(const int* __restrict__ bcntE, const unsigned int* __restrict__ ebkt,
                                               const int* __restrict__ erow, const float* __restrict__ dist,
                                               const int* __restrict__ bktbaseE, int* __restrict__ rowptrE,
                                               int* __restrict__ slist, float* __restrict__ distS,
                                               const int* __restrict__ bcntT, const unsigned int* __restrict__ tbkt,
                                               const float* __restrict__ dist_trip, const float* __restrict__ angle,
                                               const int* __restrict__ bktbaseT, int* __restrict__ rowptrT,
                                               float2* __restrict__ tpay) {
    int b = blockIdx.x;
    bool isE = b < NBK;
    if (!isE) b -= NBK;
    int tid = threadIdx.x;
    __shared__ int ccnt[64];
    __shared__ int cbase[64];
    __shared__ int nb[8];
    if (tid < 64) ccnt[tid] = 0;
    const int* bcnt = isE ? bcntE : bcntT;
    const unsigned int* bkt = isE ? ebkt : tbkt;
    if (tid < 8) nb[tid] = min(bcnt[b * 8 + tid], CAPS);
    __syncthreads();
    for (int s = 0; s < 8; ++s) {
        int n = nb[s];
        const unsigned int* src = bkt + (size_t)(b * 8 + s) * CAPS;
        for (int i = tid; i < n; i += 256) atomicAdd(&ccnt[src[i] & 63u], 1);
    }
    __syncthreads();
    if (tid < 64) {
        int v = ccnt[tid];
        int incl = v;
        #pragma unroll
        for (int s = 1; s < 64; s <<= 1) {
            int t = __shfl_up(incl, (unsigned)s, 64);
            if (tid >= s) incl += t;
        }
        int base = (isE ? bktbaseE : bktbaseT)[b];
        int excl = base + incl - v;
        cbase[tid] = excl;
        int col = b * 64 + tid;
        int* rp = isE ? rowptrE : rowptrT;
        if (col <= N_) rp[col] = excl;
        ccnt[tid] = 0;
    }
    __syncthreads();
    for (int s = 0; s < 8; ++s) {
        int n = nb[s];
        const unsigned int* src = bkt + (size_t)(b * 8 + s) * CAPS;
        for (int i = tid; i < n; i += 256) {
            unsigned int rec = src[i];
            int c = (int)(rec & 63u);
            int e = (int)(rec >> 6);
            int off = atomicAdd(&ccnt[c], 1);
            int pos = cbase[c] + off;
            if (isE) {
                slist[pos] = erow[e];
                distS[pos] = dist[e];
            } else {
                tpay[pos] = make_float2(dist_trip[e], angle[e]);
            }
        }
    }
}

// ================= weight prep =================
__global__ __launch_bounds__(256) void k_wprep(const float* __restrict__ emb_w2, const float* __restrict__ iw_down,
                                               const float* __restrict__ iw_t1, const float* __restrict__ iw_t2,
                                               const float* __restrict__ iw_up, const float* __restrict__ ow0,
                                               const float* __restrict__ ow1, unsigned short* __restrict__ Wt) {
    int mat = blockIdx.x >> 3;
    int part = blockIdx.x & 7;
    const float* src;
    if (mat == 0) src = emb_w2;
    else if (mat < 5) src = iw_down + (size_t)(mat - 1) * 16384;
    else if (mat < 9) src = iw_t1 + (size_t)(mat - 5) * 16384;
    else if (mat < 13) src = iw_t2 + (size_t)(mat - 9) * 16384;
    else if (mat < 17) src = iw_up + (size_t)(mat - 13) * 16384;
    else if (mat < 22) src = ow0 + (size_t)(mat - 17) * 16384;
    else src = ow1 + (size_t)(mat - 22) * 16384;
    unsigned short* dst = Wt + (size_t)mat * 16384;
    int base = part * 2048;
    for (int i = base + threadIdx.x; i < base + 2048; i += 256) {
        int k = i >> 7, n = i & 127;
        dst[n * 128 + k] = f2bf(src[i]);
    }
}

// ================= merged geom + basis =================
__global__ __launch_bounds__(256) void k_geomb(const float* __restrict__ distS,
                                               const float* __restrict__ freq, const float* __restrict__ iw_rbf1,
                                               float* __restrict__ rbfS, __half* __restrict__ s8all,
                                               const float2* __restrict__ tpay, const float* __restrict__ sfreq,
                                               __half* __restrict__ basis) {
    __shared__ float W1s[4][48];
    int tid = threadIdx.x;
    if (blockIdx.x < EG) {
        if (tid < 192) W1s[tid / 48][tid % 48] = iw_rbf1[tid];
        __syncthreads();
        int p = blockIdx.x * 256 + tid;
        if (p >= E_) return;
        float d = distS[p] * 0.2f;
        float d2 = d * d, d4 = d2 * d2, d5 = d4 * d;
        float env = __fdividef(1.0f, d) - 28.0f * d5 + 48.0f * d5 * d - 21.0f * d5 * d2;
        float rb[6];
        #pragma unroll
        for (int r = 0; r < 6; ++r) {
            rb[r] = env * __sinf(freq[r] * d);
            rbfS[(size_t)p * 6 + r] = rb[r];
        }
        #pragma unroll
        for (int b = 0; b < 4; ++b) {
            __half out[8];
            #pragma unroll
            for (int k = 0; k < 8; ++k) {
                float u = 0.f;
                #pragma unroll
                for (int r = 0; r < 6; ++r) u += rb[r] * W1s[b][r * 8 + k];
                out[k] = __float2half(siluf(u));
            }
            *(uint4*)&s8all[((size_t)b * E_ + p) * 8] = *(uint4*)out;
        }
    } else {
        int t = (blockIdx.x - EG) * 256 + tid;
        if (t >= T_) return;
        float2 da = tpay[t];
        float d = da.x * 0.2f;
        float a = da.y;
        float d2 = d * d, d4 = d2 * d2, d5 = d4 * d;
        float env = __fdividef(1.0f, d) - 28.0f * d5 + 48.0f * d5 * d - 21.0f * d5 * d2;
        float rb[6];
        #pragma unroll
        for (int r = 0; r < 6; ++r) rb[r] = env * __sinf(sfreq[r] * d);
        float sph[4];
        sph[0] = 1.0f; sph[1] = a; sph[2] = 1.5f * a * a - 0.5f; sph[3] = 2.5f * a * a * a - 1.5f * a;
        __half out[24];
        #pragma unroll
        for (int s = 0; s < 4; ++s)
            #pragma unroll
            for (int r = 0; r < 6; ++r) out[s * 6 + r] = __float2half(sph[s] * rb[r]);
        uint4* dst = (uint4*)(basis + (size_t)t * 24);
        dst[0] = ((uint4*)out)[0];
        dst[1] = ((uint4*)out)[1];
        dst[2] = ((uint4*)out)[2];
    }
}

// ================= merged init_x + embS (unrolled) =================
__global__ __launch_bounds__(128) void k_embSix(const float* __restrict__ atab, const int* __restrict__ z,
                                                unsigned short* __restrict__ xh,
                                                const int* __restrict__ rowptr, const float* __restrict__ rbfS,
                                                const float* __restrict__ w1, const float* __restrict__ b1,
                                                unsigned short* __restrict__ SSh) {
    int tid = threadIdx.x;
    if (blockIdx.x < NIX) {
        int t = blockIdx.x * 128 + tid;
        if (t >= N_ * 16) return;
        int node = t >> 4, q = t & 15;
        const float4* a4 = (const float4*)atab;
        float4 v0 = a4[(size_t)z[node] * 32 + q * 2];
        float4 v1 = a4[(size_t)z[node] * 32 + q * 2 + 1];
        uint4 pk;
        pk.x = f2bf2(v0.x, v0.y);
        pk.y = f2bf2(v0.z, v0.w);
        pk.z = f2bf2(v1.x, v1.y);
        pk.w = f2bf2(v1.z, v1.w);
        ((uint4*)xh)[t] = pk;
    } else {
        int node = (blockIdx.x - NIX) * 2 + (tid >> 6);
        int lane = tid & 63;
        if (node >= N_) return;
        int c = lane * 2;
        float wc0[6], wc1[6];
        #pragma unroll
        for (int r = 0; r < 6; ++r) { wc0[r] = w1[r * 128 + c]; wc1[r] = w1[r * 128 + c + 1]; }
        float bb0 = b1[c], bb1 = b1[c + 1];
        float a0 = 0.f, a1 = 0.f;
        int p0 = rowptr[node], p1 = rowptr[node + 1];
        int p = p0;
        for (; p + 4 <= p1; p += 4) {
            float2 rb[4][3];
            #pragma unroll
            for (int u = 0; u < 4; ++u) {
                const float2* r2 = (const float2*)&rbfS[(size_t)(p + u) * 6];
                rb[u][0] = r2[0]; rb[u][1] = r2[1]; rb[u][2] = r2[2];
            }
            #pragma unroll
            for (int u = 0; u < 4; ++u) {
                float u0 = bb0 + rb[u][0].x * wc0[0] + rb[u][0].y * wc0[1] + rb[u][1].x * wc0[2] +
                           rb[u][1].y * wc0[3] + rb[u][2].x * wc0[4] + rb[u][2].y * wc0[5];
                float u1 = bb1 + rb[u][0].x * wc1[0] + rb[u][0].y * wc1[1] + rb[u][1].x * wc1[2] +
                           rb[u][1].y * wc1[3] + rb[u][2].x * wc1[4] + rb[u][2].y * wc1[5];
                a0 += siluf(u0);
                a1 += siluf(u1);
            }
        }
        for (; p < p1; ++p) {
            const float2* r2 = (const float2*)&rbfS[(size_t)p * 6];
            float2 ra = r2[0], rbx = r2[1], rc = r2[2];
            float u0 = bb0 + ra.x * wc0[0] + ra.y * wc0[1] + rbx.x * wc0[2] + rbx.y * wc0[3] + rc.x * wc0[4] + rc.y * wc0[5];
            float u1 = bb1 + ra.x * wc1[0] + ra.y * wc1[1] + rbx.x * wc1[2] + rbx.y * wc1[3] + rc.x * wc1[4] + rc.y * wc1[5];
            a0 += siluf(u0);
            a1 += siluf(u1);
        }
        *(unsigned int*)&SSh[(size_t)node * 128 + c] = f2bf2(a0, a1);
    }
}

// ================= embedding GEMM + sv4 (independent, prologue only) =================
__device__ __forceinline__ void body_gemm(int bid, const unsigned short* Ap, const unsigned short* Wt,
                                          const float* bias, const int* rp, unsigned short* Ch, int M) {
    int tid = threadIdx.x;
    int wave = tid >> 6, lane = tid & 63;
    int m15 = lane & 15, quad = lane >> 4;
    int row0 = bid * 32 + wave * 16;
    int arow = row0 + m15;
    if (arow > M - 1) arow = M - 1;

    f32x4 acc[8];
    #pragma unroll
    for (int nt = 0; nt < 8; ++nt) acc[nt] = (f32x4){0.f, 0.f, 0.f, 0.f};
    #pragma unroll
    for (int kt = 0; kt < 4; ++kt) {
        int ks = kt * 32 + quad * 8;
        bf16x8 av = *(const bf16x8*)(Ap + (size_t)arow * 128 + ks);
        #pragma unroll
        for (int nt = 0; nt < 8; ++nt) {
            bf16x8 bf = *(const bf16x8*)(Wt + (size_t)(nt * 16 + m15) * 128 + ks);
            acc[nt] = __builtin_amdgcn_mfma_f32_16x16x32_bf16(av, bf, acc[nt], 0, 0, 0);
        }
    }
    #pragma unroll
    for (int nt = 0; nt < 8; ++nt) {
        int col = nt * 16 + m15;
        float bc = bias[col];
        #pragma unroll
        for (int reg = 0; reg < 4; ++reg) {
            int row = row0 + quad * 4 + reg;
            if (row < M) {
                float v = acc[nt][reg] + bc * (float)(rp[row + 1] - rp[row]);
                v += bf2f(Ch[(size_t)row * 128 + col]);
                Ch[(size_t)row * 128 + col] = f2bf(v);
            }
        }
    }
}

__device__ __forceinline__ void body_sv4(int bid, const int* rowptrT, const __half* basis,
                                         const float* iw_sbf1, float* SV4, int n) {
    int tid = threadIdx.x;
    int wave = tid >> 6, lane = tid & 63;
    int node = bid * 4 + wave * 2 + (lane >> 5);
    int sub = lane & 31;
    int blk = sub >> 3, k = sub & 7;
    if (node >= n) return;
    const float* W1 = iw_sbf1 + blk * 192;
    f16x2 w[12];
    #pragma unroll
    for (int j = 0; j < 12; ++j) {
        f16x2 t;
        t.x = (_Float16)W1[(2 * j) * 8 + k];
        t.y = (_Float16)W1[(2 * j + 1) * 8 + k];
        w[j] = t;
    }
    float acc = 0.f;
    int p0 = rowptrT[node], p1 = rowptrT[node + 1];
    for (int p = p0; p < p1; ++p) {
        union { uint4 q[3]; f16x2 h[12]; } bs;
        const uint4* bp = (const uint4*)(basis + (size_t)p * 24);
        bs.q[0] = bp[0]; bs.q[1] = bp[1]; bs.q[2] = bp[2];
        float u = 0.f;
        #pragma unroll
        for (int j = 0; j < 12; ++j) u = fdot2f(bs.h[j], w[j], u);
        acc += siluf(u);
    }
    SV4[((size_t)blk * n + node) * 8 + k] = acc;
}

__global__ __launch_bounds__(128) void k_gemmsv(const unsigned short* __restrict__ Ap,
                                                const unsigned short* __restrict__ Wt,
                                                const float* __restrict__ bias, const int* __restrict__ rp,
                                                unsigned short* __restrict__ Ch,
                                                const int* __restrict__ rowptrT, const __half* __restrict__ basis,
                                                const float* __restrict__ iw_sbf1, float* __restrict__ SV4) {
    if (blockIdx.x < GEMMG2)
        body_gemm(blockIdx.x, Ap, Wt, bias, rp, Ch, N_);
    else
        body_sv4(blockIdx.x - GEMMG2, rowptrT, basis, iw_sbf1, SV4, N_);
}

// ================= per-block MLP + extra reduction (standalone, 128 thr / 32 rows) =========
__global__ __launch_bounds__(128) void k_block_mlp(const unsigned short* __restrict__ xh,
                                                   const unsigned short* __restrict__ Wd, const float* __restrict__ bd,
                                                   const unsigned short* __restrict__ Wt1,
                                                   const unsigned short* __restrict__ Wt2, const float* __restrict__ bt2,
                                                   const unsigned short* __restrict__ Wup, const float* __restrict__ bup,
                                                   const float* __restrict__ SV, const float* __restrict__ W2,
                                                   float* __restrict__ extraP,
                                                   unsigned short* __restrict__ xuph, int M) {
    __shared__ unsigned short smh[2 * 16 * 136];
    int bid = blockIdx.x;
    int tid = threadIdx.x;
    int wave = tid >> 6, lane = tid & 63;
    int m15 = lane & 15, quad = lane >> 4;
    int row0 = bid * 32 + wave * 16;
    int arow = row0 + m15;
    if (arow > M - 1) arow = M - 1;
    unsigned short* L = smh + wave * (16 * 136);

    f32x4 accD[8], accU[8];
    #pragma unroll
    for (int nt = 0; nt < 8; ++nt) { accD[nt] = (f32x4){0.f, 0.f, 0.f, 0.f}; accU[nt] = (f32x4){0.f, 0.f, 0.f, 0.f}; }
    #pragma unroll
    for (int kt = 0; kt < 4; ++kt) {
        int ks = kt * 32 + quad * 8;
        bf16x8 av = *(const bf16x8*)(xh + (size_t)arow * 128 + ks);
        #pragma unroll
        for (int nt = 0; nt < 8; ++nt) {
            bf16x8 bd_ = *(const bf16x8*)(Wd + (size_t)(nt * 16 + m15) * 128 + ks);
            accD[nt] = __builtin_amdgcn_mfma_f32_16x16x32_bf16(av, bd_, accD[nt], 0, 0, 0);
            bf16x8 bu_ = *(const bf16x8*)(Wup + (size_t)(nt * 16 + m15) * 128 + ks);
            accU[nt] = __builtin_amdgcn_mfma_f32_16x16x32_bf16(av, bu_, accU[nt], 0, 0, 0);
        }
    }
    #pragma unroll
    for (int nt = 0; nt < 8; ++nt) {
        int col = nt * 16 + m15;
        float bcu = bup[col], bcd = bd[col];
        #pragma unroll
        for (int reg = 0; reg < 4; ++reg) {
            int row = row0 + quad * 4 + reg;
            if (row < M) xuph[(size_t)row * 128 + col] = f2bf(accU[nt][reg] + bcu);
            L[(quad * 4 + reg) * 136 + col] = f2bf(accD[nt][reg] + bcd);
        }
    }
    __syncthreads();

    #pragma unroll
    for (int nt = 0; nt < 8; ++nt) accD[nt] = (f32x4){0.f, 0.f, 0.f, 0.f};
    #pragma unroll
    for (int kt = 0; kt < 4; ++kt) {
        int ks = kt * 32 + quad * 8;
        bf16x8 av = *(const bf16x8*)(L + m15 * 136 + ks);
        #pragma unroll
        for (int nt = 0; nt < 8; ++nt) {
            bf16x8 bf = *(const bf16x8*)(Wt1 + (size_t)(nt * 16 + m15) * 128 + ks);
            accD[nt] = __builtin_amdgcn_mfma_f32_16x16x32_bf16(av, bf, accD[nt], 0, 0, 0);
        }
    }
    __syncthreads();
    #pragma unroll
    for (int nt = 0; nt < 8; ++nt) {
        int col = nt * 16 + m15;
        #pragma unroll
        for (int reg = 0; reg < 4; ++reg)
            L[(quad * 4 + reg) * 136 + col] = f2bf(siluf(accD[nt][reg]));
    }
    __syncthreads();

    #pragma unroll
    for (int nt = 0; nt < 8; ++nt) accD[nt] = (f32x4){0.f, 0.f, 0.f, 0.f};
    #pragma unroll
    for (int kt = 0; kt < 4; ++kt) {
        int ks = kt * 32 + quad * 8;
        bf16x8 av = *(const bf16x8*)(L + m15 * 136 + ks);
        #pragma unroll
        for (int nt = 0; nt < 8; ++nt) {
            bf16x8 bf = *(const bf16x8*)(Wt2 + (size_t)(nt * 16 + m15) * 128 + ks);
            accD[nt] = __builtin_amdgcn_mfma_f32_16x16x32_bf16(av, bf, accD[nt], 0, 0, 0);
        }
    }
    __syncthreads();
    // t-tile (bf16) reuses the full 32x136 scratch
    #pragma unroll
    for (int nt = 0; nt < 8; ++nt) {
        int col = nt * 16 + m15;
        float bc = bt2[col];
        #pragma unroll
        for (int reg = 0; reg < 4; ++reg)
            smh[(wave * 16 + quad * 4 + reg) * 136 + col] = f2bf(accD[nt][reg] + bc);
    }
    __syncthreads();

    int col = tid;  // 0..127
    float acc8[8];
    #pragma unroll
    for (int k = 0; k < 8; ++k) acc8[k] = 0.f;
    int rmax = M - bid * 32;
    if (rmax > 32) rmax = 32;
    for (int rr = 0; rr < rmax; ++rr) {
        float t = bf2f(smh[rr * 136 + col]);
        const float4* sv4 = (const float4*)&SV[(size_t)(bid * 32 + rr) * 8];
        float4 s0 = sv4[0], s1 = sv4[1];
        acc8[0] += t * s0.x; acc8[1] += t * s0.y; acc8[2] += t * s0.z; acc8[3] += t * s0.w;
        acc8[4] += t * s1.x; acc8[5] += t * s1.y; acc8[6] += t * s1.z; acc8[7] += t * s1.w;
    }
    float e = 0.f;
    #pragma unroll
    for (int k = 0; k < 8; ++k) e += acc8[k] * W2[k * 128 + col];
    atomicAdd(&extraP[(bid & (XSLOT - 1)) * 128 + col], e);
}

// ================= out-block MLP (standalone, 128 thr / 32 rows) =================
template <int PACC>
__global__ __launch_bounds__(128) void k_out_mlp(const unsigned short* __restrict__ hB,
                                                 const unsigned short* __restrict__ W0t, const float* __restrict__ b0,
                                                 const unsigned short* __restrict__ W1t, const float* __restrict__ b1,
                                                 const float* __restrict__ w2col, const float* __restrict__ ob2p,
                                                 float* __restrict__ Pout, int M) {
    __shared__ unsigned short lds[2][16 * 136];
    int tid = threadIdx.x;
    int wave = tid >> 6, lane = tid & 63;
    int m15 = lane & 15, quad = lane >> 4;
    int row0 = blockIdx.x * 32 + wave * 16;
    int arow = row0 + m15;
    if (arow > M - 1) arow = M - 1;
    unsigned short* L = lds[wave];

    f32x4 acc[8];
    #pragma unroll
    for (int nt = 0; nt < 8; ++nt) acc[nt] = (f32x4){0.f, 0.f, 0.f, 0.f};
    #pragma unroll
    for (int kt = 0; kt < 4; ++kt) {
        int ks = kt * 32 + quad * 8;
        bf16x8 av = *(const bf16x8*)(hB + (size_t)arow * 128 + ks);
        #pragma unroll
        for (int nt = 0; nt < 8; ++nt) {
            bf16x8 bf = *(const bf16x8*)(W0t + (size_t)(nt * 16 + m15) * 128 + ks);
            acc[nt] = __builtin_amdgcn_mfma_f32_16x16x32_bf16(av, bf, acc[nt], 0, 0, 0);
        }
    }
    #pragma unroll
    for (int nt = 0; nt < 8; ++nt) {
        int col = nt * 16 + m15;
        float bc = b0[col];
        #pragma unroll
        for (int reg = 0; reg < 4; ++reg)
            L[(quad * 4 + reg) * 136 + col] = f2bf(siluf(acc[nt][reg] + bc));
    }
    __syncthreads();

    #pragma unroll
    for (int nt = 0; nt < 8; ++nt) acc[nt] = (f32x4){0.f, 0.f, 0.f, 0.f};
    #pragma unroll
    for (int kt = 0; kt < 4; ++kt) {
        int ks = kt * 32 + quad * 8;
        bf16x8 av = *(const bf16x8*)(L + m15 * 136 + ks);
        #pragma unroll
        for (int nt = 0; nt < 8; ++nt) {
            bf16x8 bf = *(const bf16x8*)(W1t + (size_t)(nt * 16 + m15) * 128 + ks);
            acc[nt] = __builtin_amdgcn_mfma_f32_16x16x32_bf16(av, bf, acc[nt], 0, 0, 0);
        }
    }
    float w2c[8], pp[4];
    #pragma unroll
    for (int nt = 0; nt < 8; ++nt) w2c[nt] = w2col[nt * 16 + m15];
    #pragma unroll
    for (int reg = 0; reg < 4; ++reg) pp[reg] = 0.f;
    #pragma unroll
    for (int nt = 0; nt < 8; ++nt) {
        float bc = b1[nt * 16 + m15];
        #pragma unroll
        for (int reg = 0; reg < 4; ++reg)
            pp[reg] += siluf(acc[nt][reg] + bc) * w2c[nt];
    }
    #pragma unroll
    for (int reg = 0; reg < 4; ++reg) {
        float s = pp[reg];
        s += __shfl_xor(s, 1, 64);
        s += __shfl_xor(s, 2, 64);
        s += __shfl_xor(s, 4, 64);
        s += __shfl_xor(s, 8, 64);
        if (m15 == 0) {
            int row = row0 + quad * 4 + reg;
            if (row < M) {
                float r = s + ob2p[0];
                if constexpr (PACC == 2) r += Pout[row];
                Pout[row] = r;
            }
        }
    }
}

// ================= out_block gather (256 thr / 4 nodes, unroll 8) =================
__global__ __launch_bounds__(256) void k_out_gather(const int* __restrict__ rowptr, const int* __restrict__ slist,
                                                    const float* __restrict__ rbfS,
                                                    const unsigned short* __restrict__ xh,
                                                    const float* __restrict__ wrbf,
                                                    unsigned short* __restrict__ hB, int n) {
    int node = blockIdx.x * 4 + (threadIdx.x >> 6);
    int lane = threadIdx.x & 63;
    if (node >= n) return;
    int c = lane * 2;
    float wc0[6], wc1[6];
    #pragma unroll
    for (int r = 0; r < 6; ++r) { wc0[r] = wrbf[r * 128 + c]; wc1[r] = wrbf[r * 128 + c + 1]; }
    float a0 = 0.f, a1 = 0.f;
    int p0 = rowptr[node], p1 = rowptr[node + 1];
    int p = p0;
    for (; p + 8 <= p1; p += 8) {
        int ss[8];
        #pragma unroll
        for (int u = 0; u < 8; ++u) ss[u] = slist[p + u];
        unsigned int xv[8];
        #pragma unroll
        for (int u = 0; u < 8; ++u) xv[u] = *(const unsigned int*)&xh[(size_t)ss[u] * 128 + c];
        float2 rb[8][3];
        #pragma unroll
        for (int u = 0; u < 8; ++u) {
            const float2* r2 = (const float2*)&rbfS[(size_t)(p + u) * 6];
            rb[u][0] = r2[0]; rb[u][1] = r2[1]; rb[u][2] = r2[2];
        }
        #pragma unroll
        for (int u = 0; u < 8; ++u) {
            float e0 = rb[u][0].x * wc0[0] + rb[u][0].y * wc0[1] + rb[u][1].x * wc0[2] +
                       rb[u][1].y * wc0[3] + rb[u][2].x * wc0[4] + rb[u][2].y * wc0[5];
            float e1 = rb[u][0].x * wc1[0] + rb[u][0].y * wc1[1] + rb[u][1].x * wc1[2] +
                       rb[u][1].y * wc1[3] + rb[u][2].x * wc1[4] + rb[u][2].y * wc1[5];
            float2 xf = bf2x2(xv[u]);
            a0 += xf.x * e0;
            a1 += xf.y * e1;
        }
    }
    for (; p + 4 <= p1; p += 4) {
        int ss[4];
        #pragma unroll
        for (int u = 0; u < 4; ++u) ss[u] = slist[p + u];
        unsigned int xv[4];
        #pragma unroll
        for (int u = 0; u < 4; ++u) xv[u] = *(const unsigned int*)&xh[(size_t)ss[u] * 128 + c];
        float2 rb[4][3];
        #pragma unroll
        for (int u = 0; u < 4; ++u) {
            const float2* r2 = (const float2*)&rbfS[(size_t)(p + u) * 6];
            rb[u][0] = r2[0]; rb[u][1] = r2[1]; rb[u][2] = r2[2];
        }
        #pragma unroll
        for (int u = 0; u < 4; ++u) {
            float e0 = rb[u][0].x * wc0[0] + rb[u][0].y * wc0[1] + rb[u][1].x * wc0[2] +
                       rb[u][1].y * wc0[3] + rb[u][2].x * wc0[4] + rb[u][2].y * wc0[5];
            float e1 = rb[u][0].x * wc1[0] + rb[u][0].y * wc1[1] + rb[u][1].x * wc1[2] +
                       rb[u][1].y * wc1[3] + rb[u][2].x * wc1[4] + rb[u][2].y * wc1[5];
            float2 xf = bf2x2(xv[u]);
            a0 += xf.x * e0;
            a1 += xf.y * e1;
        }
    }
    for (; p < p1; ++p) {
        int src = slist[p];
        const float2* r2 = (const float2*)&rbfS[(size_t)p * 6];
        float2 ra = r2[0], rbx = r2[1], rc = r2[2];
        float e0 = ra.x * wc0[0] + ra.y * wc0[1] + rbx.x * wc0[2] + rbx.y * wc0[3] + rc.x * wc0[4] + rc.y * wc0[5];
        float e1 = ra.x * wc1[0] + ra.y * wc1[1] + rbx.x * wc1[2] + rbx.y * wc1[3] + rc.x * wc1[4] + rc.y * wc1[5];
        float2 xf = bf2x2(*(const unsigned int*)&xh[(size_t)src * 128 + c]);
        a0 += xf.x * e0;
        a1 += xf.y * e1;
    }
    *(unsigned int*)&hB[(size_t)node * 128 + c] = f2bf2(a0, a1);
}

// ================= interaction (256 thr / 4 nodes, unroll 8, XSLOT presum) =================
__global__ __launch_bounds__(256) void k_interact(const int* __restrict__ rowptr, const int* __restrict__ slist,
                                                  const __half* __restrict__ s8, const float* __restrict__ W2,
                                                  const float* __restrict__ extraP,
                                                  const unsigned short* __restrict__ xuph,
                                                  unsigned short* __restrict__ xh, int n) {
    __shared__ float exs[128];
    int tid = threadIdx.x;
    if (tid < 128) {
        float s = 0.f;
        #pragma unroll
        for (int q = 0; q < XSLOT; ++q) s += extraP[q * 128 + tid];
        exs[tid] = s;
    }
    __syncthreads();
    int node = blockIdx.x * 4 + (tid >> 6);
    int lane = tid & 63;
    if (node >= n) return;
    int c = lane * 2;
    f16x2 w2a[4], w2b[4];
    #pragma unroll
    for (int j = 0; j < 4; ++j) {
        f16x2 wa, wb;
        wa.x = (_Float16)W2[(2 * j) * 128 + c];
        wa.y = (_Float16)W2[(2 * j + 1) * 128 + c];
        wb.x = (_Float16)W2[(2 * j) * 128 + c + 1];
        wb.y = (_Float16)W2[(2 * j + 1) * 128 + c + 1];
        w2a[j] = wa;
        w2b[j] = wb;
    }
    int p0 = rowptr[node], p1 = rowptr[node + 1];
    float cntf = (float)(p1 - p0);
    float a0 = cntf * exs[c], a1 = cntf * exs[c + 1];
    int p = p0;
    for (; p + 8 <= p1; p += 8) {
        int ss[8];
        #pragma unroll
        for (int u = 0; u < 8; ++u) ss[u] = slist[p + u];
        unsigned int xv[8];
        #pragma unroll
        for (int u = 0; u < 8; ++u) xv[u] = *(const unsigned int*)&xuph[(size_t)ss[u] * 128 + c];
        uint4 sv[8];
        #pragma unroll
        for (int u = 0; u < 8; ++u) sv[u] = *(const uint4*)(s8 + (size_t)(p + u) * 8);
        #pragma unroll
        for (int u = 0; u < 8; ++u) {
            union { uint4 q; f16x2 h[4]; } s;
            s.q = sv[u];
            float e0 = fdot2f(s.h[0], w2a[0], 0.f);
            e0 = fdot2f(s.h[1], w2a[1], e0);
            e0 = fdot2f(s.h[2], w2a[2], e0);
            e0 = fdot2f(s.h[3], w2a[3], e0);
            float e1 = fdot2f(s.h[0], w2b[0], 0.f);
            e1 = fdot2f(s.h[1], w2b[1], e1);
            e1 = fdot2f(s.h[2], w2b[2], e1);
            e1 = fdot2f(s.h[3], w2b[3], e1);
            float2 xf = bf2x2(xv[u]);
            a0 += xf.x * e0;
            a1 += xf.y * e1;
        }
    }
    for (; p + 4 <= p1; p += 4) {
        int ss[4];
        #pragma unroll
        for (int u = 0; u < 4; ++u) ss[u] = slist[p + u];
        unsigned int xv[4];
        #pragma unroll
        for (int u = 0; u < 4; ++u) xv[u] = *(const unsigned int*)&xuph[(size_t)ss[u] * 128 + c];
        uint4 sv[4];
        #pragma unroll
        for (int u = 0; u < 4; ++u) sv[u] = *(const uint4*)(s8 + (size_t)(p + u) * 8);
        #pragma unroll
        for (int u = 0; u < 4; ++u) {
            union { uint4 q; f16x2 h[4]; } s;
            s.q = sv[u];
            float e0 = fdot2f(s.h[0], w2a[0], 0.f);
            e0 = fdot2f(s.h[1], w2a[1], e0);
            e0 = fdot2f(s.h[2], w2a[2], e0);
            e0 = fdot2f(s.h[3], w2a[3], e0);
            float e1 = fdot2f(s.h[0], w2b[0], 0.f);
            e1 = fdot2f(s.h[1], w2b[1], e1);
            e1 = fdot2f(s.h[2], w2b[2], e1);
            e1 = fdot2f(s.h[3], w2b[3], e1);
            float2 xf = bf2x2(xv[u]);
            a0 += xf.x * e0;
            a1 += xf.y * e1;
        }
    }
    for (; p < p1; ++p) {
        int src = slist[p];
        float2 xf = bf2x2(*(const unsigned int*)&xuph[(size_t)src * 128 + c]);
        union { uint4 q; f16x2 h[4]; } s;
        s.q = *(const uint4*)(s8 + (size_t)p * 8);
        float e0 = fdot2f(s.h[0], w2a[0], 0.f);
        e0 = fdot2f(s.h[1], w2a[1], e0);
        e0 = fdot2f(s.h[2], w2a[2], e0);
        e0 = fdot2f(s.h[3], w2a[3], e0);
        float e1 = fdot2f(s.h[0], w2b[0], 0.f);
        e1 = fdot2f(s.h[1], w2b[1], e1);
        e1 = fdot2f(s.h[2], w2b[2], e1);
        e1 = fdot2f(s.h[3], w2b[3], e1);
        a0 += xf.x * e0;
        a1 += xf.y * e1;
    }
    unsigned int cur = *(unsigned int*)&xh[(size_t)node * 128 + c];
    float2 xc = bf2x2(cur);
    *(unsigned int*)&xh[(size_t)node * 128 + c] = f2bf2(xc.x + a0, xc.y + a1);
}

// ================= pooling =================
__global__ __launch_bounds__(256) void k_pool(const float* __restrict__ P, const int* __restrict__ batch,
                                              float* __restrict__ pool, float* __restrict__ cnt, int n) {
    int i = blockIdx.x * 256 + threadIdx.x;
    int lane = threadIdx.x & 63;
    int b = (i < n) ? batch[i] : -1;
    float p = (i < n) ? P[i] : 0.f;
    int b0 = __shfl(b, 0, 64);
    int b63 = __shfl(b, 63, 64);
    if (b0 == b63 && b0 >= 0) {
        float s = p;
        #pragma unroll
        for (int off = 32; off > 0; off >>= 1) s += __shfl_xor(s, off, 64);
        if (lane == 0) {
            atomicAdd(&pool[b0], s);
            atomicAdd(&cnt[b0], 64.0f);
        }
    } else {
        if (i < n) {
            atomicAdd(&pool[b], p);
            atomicAdd(&cnt[b], 1.0f);
        }
    }
}

__global__ __launch_bounds__(64) void k_final(const float* __restrict__ pool, const float* __restrict__ cnt,
                                              float* __restrict__ out) {
    int g = threadIdx.x;
    if (g < G_) out[g] = __fdividef(pool[g], fmaxf(cnt[g], 1.0f));
}

extern "C" void kernel_launch(void* const* d_in, const int* in_sizes, int n_in,
                              void* d_out, int out_size, void* d_ws, size_t ws_size,
                              hipStream_t stream) {
    (void)in_sizes; (void)n_in; (void)out_size; (void)ws_size;
    const int* z = (const int*)d_in[0];
    const float* dist = (const float*)d_in[1];
    const float* dist_trip = (const float*)d_in[2];
    const float* angle = (const float*)d_in[3];
    const int* edge_index = (const int*)d_in[4];
    const int* triplets = (const int*)d_in[5];
    const int* batch = (const int*)d_in[6];
    const float* atom_table = (const float*)d_in[7];
    const float* rbf_freq = (const float*)d_in[8];
    const float* sbf_freq = (const float*)d_in[9];
    const float* emb_w1 = (const float*)d_in[10];
    const float* emb_b1 = (const float*)d_in[11];
    const float* emb_w2 = (const float*)d_in[12];
    const float* emb_b2 = (const float*)d_in[13];
    const float* iw_rbf1 = (const float*)d_in[14];
    const float* iw_rbf2 = (const float*)d_in[15];
    const float* iw_sbf1 = (const float*)d_in[16];
    const float* iw_sbf2 = (const float*)d_in[17];
    const float* iw_t1 = (const float*)d_in[18];
    const float* iw_t2 = (const float*)d_in[19];
    const float* ib_t2 = (const float*)d_in[20];
    const float* iw_up = (const float*)d_in[21];
    const float* ib_up = (const float*)d_in[22];
    const float* iw_down = (const float*)d_in[23];
    const float* ib_down = (const float*)d_in[24];
    const float* ow_rbf = (const float*)d_in[25];
    const float* ow0 = (const float*)d_in[26];
    const float* ob0 = (const float*)d_in[27];
    const float* ow1 = (const float*)d_in[28];
    const float* ob1 = (const float*)d_in[29];
    const float* ow2 = (const float*)d_in[30];
    const float* ob2 = (const float*)d_in[31];

    const int* erow = edge_index;
    const int* ecol = edge_index + E_;

    // workspace layout
    float* ws = (float*)d_ws;
    float* bufA = ws;                          // N*128 (embS bf16 out)
    float* bufB = bufA + (size_t)N_ * H_;      // N*128 (hB bf16)
    float* P = bufB + (size_t)N_ * H_;         // N
    float* rbfS = P + N_;                      // E*6 (CSR order)
    float* SV4 = rbfS + (size_t)E_ * 6;        // 4*N*8
    float* extra4 = SV4 + (size_t)4 * N_ * 8;  // 4 * XSLOT * 128
    float* pool = extra4 + 4 * XSLOT * 128;    // G
    float* cnt = pool + G_;                    // G
    int* bcntE = (int*)(cnt + G_);             // NSB
    int* bcntT = bcntE + NSB;                  // NSB
    int* bktbaseE = bcntT + NSB;               // NBK
    int* bktbaseT = bktbaseE + NBK;            // NBK
    int* rowptr = bktbaseT + NBK;              // N+1
    int* rowptrT = rowptr + N_ + 1;            // N+1
    int* slist = rowptrT + N_ + 1;             // E
    float* distS = (float*)(slist + E_);       // E
    uintptr_t tp = (uintptr_t)(distS + E_);
    tp = (tp + 7) & ~(uintptr_t)7;
    float2* tpay = (float2*)tp;                // T float2
    __half* s8all = (__half*)(tpay + T_);      // 4*E*8 halves
    __half* basis = s8all + (size_t)4 * E_ * 8;                          // T*24 halves
    unsigned short* xh = (unsigned short*)(basis + (size_t)T_ * 24);     // N*128 bf16 node state
    unsigned short* xuph = xh + (size_t)N_ * H_;                          // N*128 bf16 x_up
    unsigned short* Wt = xuph + (size_t)N_ * H_;                          // 27*16384 bf16 weights
    unsigned short* hB = (unsigned short*)bufB;

    // bucket arrays alias s8all region (written later by k_geomb) — 4B packed records
    unsigned int* ebkt = (unsigned int*)s8all;               // NSB*CAPS uint = 12.8MB
    unsigned int* tbkt = ebkt + (size_t)NSB * CAPS;          // NSB*CAPS uint = 12.8MB

    hipMemsetAsync(extra4, 0, (4 * XSLOT * 128 + 2 * G_ + 2 * NSB) * sizeof(float), stream);
    k_wprep<<<27 * 8, 256, 0, stream>>>(emb_w2, iw_down, iw_t1, iw_t2, iw_up, ow0, ow1, Wt);
    k_bucket<<<EB + TB, 256, 0, stream>>>(ecol, triplets, bcntE, ebkt, bcntT, tbkt);
    k_scanB<<<2, 1024, 0, stream>>>(bcntE, bktbaseE, bcntT, bktbaseT);
    k_place<<<2 * NBK, 256, 0, stream>>>(bcntE, ebkt, erow, dist, bktbaseE, rowptr, slist, distS,
                                         bcntT, tbkt, dist_trip, angle, bktbaseT, rowptrT, tpay);

    k_geomb<<<EG + TG, 256, 0, stream>>>(distS, rbf_freq, iw_rbf1, rbfS, s8all,
                                         tpay, sbf_freq, basis);
    k_embSix<<<NIX + NG2, 128, 0, stream>>>(atom_table, z, xh, rowptr, rbfS, emb_w1, emb_b1,
                                            (unsigned short*)bufA);
    k_gemmsv<<<GEMMG2 + SVG, 128, 0, stream>>>((unsigned short*)bufA, Wt, emb_b2, rowptr, xh,
                                               rowptrT, basis, iw_sbf1, SV4);

    auto out_block = [&](int k, bool first) {
        k_out_gather<<<NG4, 256, 0, stream>>>(rowptr, slist, rbfS, xh,
                                              ow_rbf + (size_t)k * 6 * 128, hB, N_);
        if (first)
            k_out_mlp<1><<<GEMMG2, 128, 0, stream>>>(hB, Wt + (size_t)(17 + k) * 16384, ob0 + k * 128,
                                                     Wt + (size_t)(22 + k) * 16384, ob1 + k * 128,
                                                     ow2 + k * 128, ob2 + k, P, N_);
        else
            k_out_mlp<2><<<GEMMG2, 128, 0, stream>>>(hB, Wt + (size_t)(17 + k) * 16384, ob0 + k * 128,
                                                     Wt + (size_t)(22 + k) * 16384, ob1 + k * 128,
                                                     ow2 + k * 128, ob2 + k, P, N_);
    };

    out_block(0, true);

    for (int b = 0; b < 4; ++b) {
        k_block_mlp<<<GEMMG2, 128, 0, stream>>>(xh,
                                                Wt + (size_t)(1 + b) * 16384, ib_down + b * 128,
                                                Wt + (size_t)(5 + b) * 16384,
                                                Wt + (size_t)(9 + b) * 16384, ib_t2 + b * 128,
                                                Wt + (size_t)(13 + b) * 16384, ib_up + b * 128,
                                                SV4 + (size_t)b * N_ * 8,
                                                iw_sbf2 + (size_t)b * 1024,
                                                extra4 + (size_t)b * XSLOT * 128,
                                                xuph, N_);
        k_interact<<<NG4, 256, 0, stream>>>(rowptr, slist, s8all + (size_t)b * E_ * 8,
                                            iw_rbf2 + (size_t)b * 1024, extra4 + (size_t)b * XSLOT * 128,
                                            xuph, xh, N_);
        out_block(b + 1, false);
    }

    k_pool<<<(N_ + 255) / 256, 256, 0, stream>>>(P, batch, pool, cnt, N_);
    k_final<<<1, 64, 0, stream>>>(pool, cnt, (float*)d_out);
}

// Round 7
// 1418.201 us; speedup vs baseline: 1.0810x; 1.0355x over previous
//
#include <hip/hip_runtime.h>
#include <hip/hip_fp16.h>

#define N_ 50000
#define E_ 800000
#define T_ 800000
#define G_ 64
#define H_ 128

// bucket sort geometry: 64 cols per bucket, 8 XCD-affine sub-buckets each
#define NBK 782            // ceil(N/64)
#define NSB (NBK * 8)      // 6256 sub-buckets
#define CAPS 512           // entries per sub-bucket (mean ~128)
#define CHUNK 4096         // elements per k_bucket block
#define EB ((E_ + CHUNK - 1) / CHUNK)   // 196
#define TB ((T_ + CHUNK - 1) / CHUNK)   // 196
#define XSLOT 16           // extra-reduction atomic slots

#define GEMMG2 ((N_ + 31) / 32)     // 1563 MFMA blocks (128 thr / 32 rows)
#define NG2 ((N_ + 1) / 2)          // 25000 embS blocks (128 thr / 2 nodes)
#define NG4 ((N_ + 3) / 4)          // 12500 gather blocks (256 thr / 4 nodes)
#define NIX ((N_ * 16 + 127) / 128) // 6250 init_x blocks
#define SVG ((N_ + 3) / 4)          // 12500 sv4 blocks (128 thr / 4 nodes)
#define EG ((E_ + 255) / 256)
#define TG ((T_ + 255) / 256)

typedef __attribute__((ext_vector_type(8))) short bf16x8;
typedef __attribute__((ext_vector_type(4))) float f32x4;
typedef _Float16 f16x2 __attribute__((ext_vector_type(2)));

__device__ __forceinline__ float siluf(float v) {
    return __fdividef(v, 1.0f + __expf(-v));
}

__device__ __forceinline__ unsigned short f2bf(float f) {
    unsigned int u = __float_as_uint(f);
    u += 0x7fffu + ((u >> 16) & 1u);
    return (unsigned short)(u >> 16);
}
__device__ __forceinline__ unsigned int f2bf2(float a, float b) {
    return (unsigned int)f2bf(a) | ((unsigned int)f2bf(b) << 16);
}
__device__ __forceinline__ float bf2f(unsigned short h) {
    return __uint_as_float(((unsigned int)h) << 16);
}
__device__ __forceinline__ float2 bf2x2(unsigned int p) {
    return make_float2(__uint_as_float(p << 16), __uint_as_float(p & 0xffff0000u));
}
__device__ __forceinline__ float fdot2f(f16x2 a, f16x2 b, float c) {
    return __builtin_amdgcn_fdot2(a, b, c, false);
}

// ================= CSR build =================
__global__ __launch_bounds__(256) void k_bucket(const int* __restrict__ ecol,
                                                const int* __restrict__ trip,
                                                int* bcntE, unsigned int* __restrict__ ebkt,
                                                int* bcntT, unsigned int* __restrict__ tbkt) {
    __shared__ int hist[NBK];
    __shared__ int bbase[NBK];
    int blk = blockIdx.x;
    bool isE = blk < EB;
    int ebase = (isE ? blk : blk - EB) * CHUNK;
    const int nElem = isE ? E_ : T_;
    int r = blk & 7;
    int* bcnt = isE ? bcntE : bcntT;
    unsigned int* bkt = isE ? ebkt : tbkt;
    int tid = threadIdx.x;

    for (int i = tid; i < NBK; i += 256) hist[i] = 0;
    __syncthreads();

    int cols[16];
    #pragma unroll
    for (int u = 0; u < 16; ++u) {
        int idx = ebase + u * 256 + tid;
        int c = -1;
        if (idx < nElem) c = isE ? ecol[idx] : trip[3 * idx + 1];
        cols[u] = c;
        if (c >= 0) atomicAdd(&hist[c >> 6], 1);
    }
    __syncthreads();

    for (int b = tid; b < NBK; b += 256) {
        int c = hist[b];
        bbase[b] = c ? atomicAdd(&bcnt[b * 8 + r], c) : 0;
        hist[b] = 0;
    }
    __syncthreads();

    #pragma unroll
    for (int u = 0; u < 16; ++u) {
        int c = cols[u];
        if (c >= 0) {
            int bk = c >> 6;
            int off = atomicAdd(&hist[bk], 1);
            int pos = bbase[bk] + off;
            if (pos < CAPS) {
                int idx = ebase + u * 256 + tid;
                bkt[(size_t)(bk * 8 + r) * CAPS + pos] =
                    ((unsigned int)idx << 6) | (unsigned int)(c & 63);
            }
        }
    }
}

__global__ __launch_bounds__(1024) void k_scanB(const int* __restrict__ bcntE, int* bktbaseE,
                                                const int* __restrict__ bcntT, int* bktbaseT) {
    const int* bcnt = (blockIdx.x == 0) ? bcntE : bcntT;
    int* bb = (blockIdx.x == 0) ? bktbaseE : bktbaseT;
    int tid = threadIdx.x, lane = tid & 63, w = tid >> 6;
    __shared__ int wsum[16];
    int v = 0;
    if (tid < NBK) {
        #pragma unroll
        for (int s = 0; s < 8; ++s) v += min(bcnt[tid * 8 + s], CAPS);
    }
    int incl = v;
    #pragma unroll
    for (int s = 1; s < 64; s <<= 1) {
        int t = __shfl_up(incl, (unsigned)s, 64);
        if (lane >= s) incl += t;
    }
    if (lane == 63) wsum[w] = incl;
    __syncthreads();
    int wexcl = 0;
    for (int j = 0; j < w; ++j) wexcl += wsum[j];
    if (tid < NBK) bb[tid] = wexcl + incl - v;
}

__global__ __launch_bounds__(256) void k_place(const int* __restrict__ bcntE, const unsigned int* __restrict__ ebkt,
                                               const int* __restrict__ erow, const float* __restrict__ dist,
                                               const int* __restrict__ bktbaseE, int* __restrict__ rowptrE,
                                               int* __restrict__ slist, float* __restrict__ distS,
                                               const int* __restrict__ bcntT, const unsigned int* __restrict__ tbkt,
                                               const float* __restrict__ dist_trip, const float* __restrict__ angle,
                                               const int* __restrict__ bktbaseT, int* __restrict__ rowptrT,
                                               float2* __restrict__ tpay) {
    int b = blockIdx.x;
    bool isE = b < NBK;
    if (!isE) b -= NBK;
    int tid = threadIdx.x;
    __shared__ int ccnt[64];
    __shared__ int cbase[64];
    __shared__ int nb[8];
    if (tid < 64) ccnt[tid] = 0;
    const int* bcnt = isE ? bcntE : bcntT;
    const unsigned int* bkt = isE ? ebkt : tbkt;
    if (tid < 8) nb[tid] = min(bcnt[b * 8 + tid], CAPS);
    __syncthreads();
    for (int s = 0; s < 8; ++s) {
        int n = nb[s];
        const unsigned int* src = bkt + (size_t)(b * 8 + s) * CAPS;
        for (int i = tid; i < n; i += 256) atomicAdd(&ccnt[src[i] & 63u], 1);
    }
    __syncthreads();
    if (tid < 64) {
        int v = ccnt[tid];
        int incl = v;
        #pragma unroll
        for (int s = 1; s < 64; s <<= 1) {
            int t = __shfl_up(incl, (unsigned)s, 64);
            if (tid >= s) incl += t;
        }
        int base = (isE ? bktbaseE : bktbaseT)[b];
        int excl = base + incl - v;
        cbase[tid] = excl;
        int col = b * 64 + tid;
        int* rp = isE ? rowptrE : rowptrT;
        if (col <= N_) rp[col] = excl;
        ccnt[tid] = 0;
    }
    __syncthreads();
    for (int s = 0; s < 8; ++s) {
        int n = nb[s];
        const unsigned int* src = bkt + (size_t)(b * 8 + s) * CAPS;
        for (int i = tid; i < n; i += 256) {
            unsigned int rec = src[i];
            int c = (int)(rec & 63u);
            int e = (int)(rec >> 6);
            int off = atomicAdd(&ccnt[c], 1);
            int pos = cbase[c] + off;
            if (isE) {
                slist[pos] = erow[e];
                distS[pos] = dist[e];
            } else {
                tpay[pos] = make_float2(dist_trip[e], angle[e]);
            }
        }
    }
}

// ================= weight prep =================
__global__ __launch_bounds__(256) void k_wprep(const float* __restrict__ emb_w2, const float* __restrict__ iw_down,
                                               const float* __restrict__ iw_t1, const float* __restrict__ iw_t2,
                                               const float* __restrict__ iw_up, const float* __restrict__ ow0,
                                               const float* __restrict__ ow1, unsigned short* __restrict__ Wt) {
    int mat = blockIdx.x >> 3;
    int part = blockIdx.x & 7;
    const float* src;
    if (mat == 0) src = emb_w2;
    else if (mat < 5) src = iw_down + (size_t)(mat - 1) * 16384;
    else if (mat < 9) src = iw_t1 + (size_t)(mat - 5) * 16384;
    else if (mat < 13) src = iw_t2 + (size_t)(mat - 9) * 16384;
    else if (mat < 17) src = iw_up + (size_t)(mat - 13) * 16384;
    else if (mat < 22) src = ow0 + (size_t)(mat - 17) * 16384;
    else src = ow1 + (size_t)(mat - 22) * 16384;
    unsigned short* dst = Wt + (size_t)mat * 16384;
    int base = part * 2048;
    for (int i = base + threadIdx.x; i < base + 2048; i += 256) {
        int k = i >> 7, n = i & 127;
        dst[n * 128 + k] = f2bf(src[i]);
    }
}

// ================= merged geom + basis =================
__global__ __launch_bounds__(256) void k_geomb(const float* __restrict__ distS,
                                               const float* __restrict__ freq, const float* __restrict__ iw_rbf1,
                                               float* __restrict__ rbfS, __half* __restrict__ s8all,
                                               const float2* __restrict__ tpay, const float* __restrict__ sfreq,
                                               __half* __restrict__ basis) {
    __shared__ float W1s[4][48];
    int tid = threadIdx.x;
    if (blockIdx.x < EG) {
        if (tid < 192) W1s[tid / 48][tid % 48] = iw_rbf1[tid];
        __syncthreads();
        int p = blockIdx.x * 256 + tid;
        if (p >= E_) return;
        float d = distS[p] * 0.2f;
        float d2 = d * d, d4 = d2 * d2, d5 = d4 * d;
        float env = __fdividef(1.0f, d) - 28.0f * d5 + 48.0f * d5 * d - 21.0f * d5 * d2;
        float rb[6];
        #pragma unroll
        for (int r = 0; r < 6; ++r) {
            rb[r] = env * __sinf(freq[r] * d);
            rbfS[(size_t)p * 6 + r] = rb[r];
        }
        #pragma unroll
        for (int b = 0; b < 4; ++b) {
            __half out[8];
            #pragma unroll
            for (int k = 0; k < 8; ++k) {
                float u = 0.f;
                #pragma unroll
                for (int r = 0; r < 6; ++r) u += rb[r] * W1s[b][r * 8 + k];
                out[k] = __float2half(siluf(u));
            }
            *(uint4*)&s8all[((size_t)b * E_ + p) * 8] = *(uint4*)out;
        }
    } else {
        int t = (blockIdx.x - EG) * 256 + tid;
        if (t >= T_) return;
        float2 da = tpay[t];
        float d = da.x * 0.2f;
        float a = da.y;
        float d2 = d * d, d4 = d2 * d2, d5 = d4 * d;
        float env = __fdividef(1.0f, d) - 28.0f * d5 + 48.0f * d5 * d - 21.0f * d5 * d2;
        float rb[6];
        #pragma unroll
        for (int r = 0; r < 6; ++r) rb[r] = env * __sinf(sfreq[r] * d);
        float sph[4];
        sph[0] = 1.0f; sph[1] = a; sph[2] = 1.5f * a * a - 0.5f; sph[3] = 2.5f * a * a * a - 1.5f * a;
        __half out[24];
        #pragma unroll
        for (int s = 0; s < 4; ++s)
            #pragma unroll
            for (int r = 0; r < 6; ++r) out[s * 6 + r] = __float2half(sph[s] * rb[r]);
        uint4* dst = (uint4*)(basis + (size_t)t * 24);
        dst[0] = ((uint4*)out)[0];
        dst[1] = ((uint4*)out)[1];
        dst[2] = ((uint4*)out)[2];
    }
}

// ================= merged init_x + embS (unrolled) =================
__global__ __launch_bounds__(128) void k_embSix(const float* __restrict__ atab, const int* __restrict__ z,
                                                unsigned short* __restrict__ xh,
                                                const int* __restrict__ rowptr, const float* __restrict__ rbfS,
                                                const float* __restrict__ w1, const float* __restrict__ b1,
                                                unsigned short* __restrict__ SSh) {
    int tid = threadIdx.x;
    if (blockIdx.x < NIX) {
        int t = blockIdx.x * 128 + tid;
        if (t >= N_ * 16) return;
        int node = t >> 4, q = t & 15;
        const float4* a4 = (const float4*)atab;
        float4 v0 = a4[(size_t)z[node] * 32 + q * 2];
        float4 v1 = a4[(size_t)z[node] * 32 + q * 2 + 1];
        uint4 pk;
        pk.x = f2bf2(v0.x, v0.y);
        pk.y = f2bf2(v0.z, v0.w);
        pk.z = f2bf2(v1.x, v1.y);
        pk.w = f2bf2(v1.z, v1.w);
        ((uint4*)xh)[t] = pk;
    } else {
        int node = (blockIdx.x - NIX) * 2 + (tid >> 6);
        int lane = tid & 63;
        if (node >= N_) return;
        int c = lane * 2;
        float wc0[6], wc1[6];
        #pragma unroll
        for (int r = 0; r < 6; ++r) { wc0[r] = w1[r * 128 + c]; wc1[r] = w1[r * 128 + c + 1]; }
        float bb0 = b1[c], bb1 = b1[c + 1];
        float a0 = 0.f, a1 = 0.f;
        int p0 = rowptr[node], p1 = rowptr[node + 1];
        int p = p0;
        for (; p + 4 <= p1; p += 4) {
            float2 rb[4][3];
            #pragma unroll
            for (int u = 0; u < 4; ++u) {
                const float2* r2 = (const float2*)&rbfS[(size_t)(p + u) * 6];
                rb[u][0] = r2[0]; rb[u][1] = r2[1]; rb[u][2] = r2[2];
            }
            #pragma unroll
            for (int u = 0; u < 4; ++u) {
                float u0 = bb0 + rb[u][0].x * wc0[0] + rb[u][0].y * wc0[1] + rb[u][1].x * wc0[2] +
                           rb[u][1].y * wc0[3] + rb[u][2].x * wc0[4] + rb[u][2].y * wc0[5];
                float u1 = bb1 + rb[u][0].x * wc1[0] + rb[u][0].y * wc1[1] + rb[u][1].x * wc1[2] +
                           rb[u][1].y * wc1[3] + rb[u][2].x * wc1[4] + rb[u][2].y * wc1[5];
                a0 += siluf(u0);
                a1 += siluf(u1);
            }
        }
        for (; p < p1; ++p) {
            const float2* r2 = (const float2*)&rbfS[(size_t)p * 6];
            float2 ra = r2[0], rbx = r2[1], rc = r2[2];
            float u0 = bb0 + ra.x * wc0[0] + ra.y * wc0[1] + rbx.x * wc0[2] + rbx.y * wc0[3] + rc.x * wc0[4] + rc.y * wc0[5];
            float u1 = bb1 + ra.x * wc1[0] + ra.y * wc1[1] + rbx.x * wc1[2] + rbx.y * wc1[3] + rc.x * wc1[4] + rc.y * wc1[5];
            a0 += siluf(u0);
            a1 += siluf(u1);
        }
        *(unsigned int*)&SSh[(size_t)node * 128 + c] = f2bf2(a0, a1);
    }
}

// ================= embedding GEMM + sv4 (fused prologue) =================
__device__ __forceinline__ void body_gemm(int bid, const unsigned short* Ap, const unsigned short* Wt,
                                          const float* bias, const int* rp, unsigned short* Ch, int M) {
    int tid = threadIdx.x;
    int wave = tid >> 6, lane = tid & 63;
    int m15 = lane & 15, quad = lane >> 4;
    int row0 = bid * 32 + wave * 16;
    int arow = row0 + m15;
    if (arow > M - 1) arow = M - 1;

    f32x4 acc[8];
    #pragma unroll
    for (int nt = 0; nt < 8; ++nt) acc[nt] = (f32x4){0.f, 0.f, 0.f, 0.f};
    #pragma unroll
    for (int kt = 0; kt < 4; ++kt) {
        int ks = kt * 32 + quad * 8;
        bf16x8 av = *(const bf16x8*)(Ap + (size_t)arow * 128 + ks);
        #pragma unroll
        for (int nt = 0; nt < 8; ++nt) {
            bf16x8 bf = *(const bf16x8*)(Wt + (size_t)(nt * 16 + m15) * 128 + ks);
            acc[nt] = __builtin_amdgcn_mfma_f32_16x16x32_bf16(av, bf, acc[nt], 0, 0, 0);
        }
    }
    #pragma unroll
    for (int nt = 0; nt < 8; ++nt) {
        int col = nt * 16 + m15;
        float bc = bias[col];
        #pragma unroll
        for (int reg = 0; reg < 4; ++reg) {
            int row = row0 + quad * 4 + reg;
            if (row < M) {
                float v = acc[nt][reg] + bc * (float)(rp[row + 1] - rp[row]);
                v += bf2f(Ch[(size_t)row * 128 + col]);
                Ch[(size_t)row * 128 + col] = f2bf(v);
            }
        }
    }
}

__device__ __forceinline__ void body_sv4(int bid, const int* rowptrT, const __half* basis,
                                         const float* iw_sbf1, float* SV4, int n) {
    int tid = threadIdx.x;
    int wave = tid >> 6, lane = tid & 63;
    int node = bid * 4 + wave * 2 + (lane >> 5);
    int sub = lane & 31;
    int blk = sub >> 3, k = sub & 7;
    if (node >= n) return;
    const float* W1 = iw_sbf1 + blk * 192;
    f16x2 w[12];
    #pragma unroll
    for (int j = 0; j < 12; ++j) {
        f16x2 t;
        t.x = (_Float16)W1[(2 * j) * 8 + k];
        t.y = (_Float16)W1[(2 * j + 1) * 8 + k];
        w[j] = t;
    }
    float acc = 0.f;
    int p0 = rowptrT[node], p1 = rowptrT[node + 1];
    for (int p = p0; p < p1; ++p) {
        union { uint4 q[3]; f16x2 h[12]; } bs;
        const uint4* bp = (const uint4*)(basis + (size_t)p * 24);
        bs.q[0] = bp[0]; bs.q[1] = bp[1]; bs.q[2] = bp[2];
        float u = 0.f;
        #pragma unroll
        for (int j = 0; j < 12; ++j) u = fdot2f(bs.h[j], w[j], u);
        acc += siluf(u);
    }
    SV4[((size_t)blk * n + node) * 8 + k] = acc;
}

__global__ __launch_bounds__(128) void k_gemmsv(const unsigned short* __restrict__ Ap,
                                                const unsigned short* __restrict__ Wt,
                                                const float* __restrict__ bias, const int* __restrict__ rp,
                                                unsigned short* __restrict__ Ch,
                                                const int* __restrict__ rowptrT, const __half* __restrict__ basis,
                                                const float* __restrict__ iw_sbf1, float* __restrict__ SV4) {
    if (blockIdx.x < GEMMG2)
        body_gemm(blockIdx.x, Ap, Wt, bias, rp, Ch, N_);
    else
        body_sv4(blockIdx.x - GEMMG2, rowptrT, basis, iw_sbf1, SV4, N_);
}

// ================= MLP bodies (128 thr / 32 rows) =================
__device__ __forceinline__ void body_block_mlp(int bid, unsigned short* smh,
                                               const unsigned short* xh,
                                               const unsigned short* Wd, const float* bd,
                                               const unsigned short* Wt1,
                                               const unsigned short* Wt2, const float* bt2,
                                               const unsigned short* Wup, const float* bup,
                                               const float* SV, const float* W2,
                                               float* extraP, unsigned short* xuph, int M) {
    int tid = threadIdx.x;
    int wave = tid >> 6, lane = tid & 63;
    int m15 = lane & 15, quad = lane >> 4;
    int row0 = bid * 32 + wave * 16;
    int arow = row0 + m15;
    if (arow > M - 1) arow = M - 1;
    unsigned short* L = smh + wave * (16 * 136);

    f32x4 accD[8], accU[8];
    #pragma unroll
    for (int nt = 0; nt < 8; ++nt) { accD[nt] = (f32x4){0.f, 0.f, 0.f, 0.f}; accU[nt] = (f32x4){0.f, 0.f, 0.f, 0.f}; }
    #pragma unroll
    for (int kt = 0; kt < 4; ++kt) {
        int ks = kt * 32 + quad * 8;
        bf16x8 av = *(const bf16x8*)(xh + (size_t)arow * 128 + ks);
        #pragma unroll
        for (int nt = 0; nt < 8; ++nt) {
            bf16x8 bd_ = *(const bf16x8*)(Wd + (size_t)(nt * 16 + m15) * 128 + ks);
            accD[nt] = __builtin_amdgcn_mfma_f32_16x16x32_bf16(av, bd_, accD[nt], 0, 0, 0);
            bf16x8 bu_ = *(const bf16x8*)(Wup + (size_t)(nt * 16 + m15) * 128 + ks);
            accU[nt] = __builtin_amdgcn_mfma_f32_16x16x32_bf16(av, bu_, accU[nt], 0, 0, 0);
        }
    }
    #pragma unroll
    for (int nt = 0; nt < 8; ++nt) {
        int col = nt * 16 + m15;
        float bcu = bup[col], bcd = bd[col];
        #pragma unroll
        for (int reg = 0; reg < 4; ++reg) {
            int row = row0 + quad * 4 + reg;
            if (row < M) xuph[(size_t)row * 128 + col] = f2bf(accU[nt][reg] + bcu);
            L[(quad * 4 + reg) * 136 + col] = f2bf(accD[nt][reg] + bcd);
        }
    }
    __syncthreads();

    #pragma unroll
    for (int nt = 0; nt < 8; ++nt) accD[nt] = (f32x4){0.f, 0.f, 0.f, 0.f};
    #pragma unroll
    for (int kt = 0; kt < 4; ++kt) {
        int ks = kt * 32 + quad * 8;
        bf16x8 av = *(const bf16x8*)(L + m15 * 136 + ks);
        #pragma unroll
        for (int nt = 0; nt < 8; ++nt) {
            bf16x8 bf = *(const bf16x8*)(Wt1 + (size_t)(nt * 16 + m15) * 128 + ks);
            accD[nt] = __builtin_amdgcn_mfma_f32_16x16x32_bf16(av, bf, accD[nt], 0, 0, 0);
        }
    }
    __syncthreads();
    #pragma unroll
    for (int nt = 0; nt < 8; ++nt) {
        int col = nt * 16 + m15;
        #pragma unroll
        for (int reg = 0; reg < 4; ++reg)
            L[(quad * 4 + reg) * 136 + col] = f2bf(siluf(accD[nt][reg]));
    }
    __syncthreads();

    #pragma unroll
    for (int nt = 0; nt < 8; ++nt) accD[nt] = (f32x4){0.f, 0.f, 0.f, 0.f};
    #pragma unroll
    for (int kt = 0; kt < 4; ++kt) {
        int ks = kt * 32 + quad * 8;
        bf16x8 av = *(const bf16x8*)(L + m15 * 136 + ks);
        #pragma unroll
        for (int nt = 0; nt < 8; ++nt) {
            bf16x8 bf = *(const bf16x8*)(Wt2 + (size_t)(nt * 16 + m15) * 128 + ks);
            accD[nt] = __builtin_amdgcn_mfma_f32_16x16x32_bf16(av, bf, accD[nt], 0, 0, 0);
        }
    }
    __syncthreads();
    // t-tile (bf16) reuses the full 32x136 scratch
    #pragma unroll
    for (int nt = 0; nt < 8; ++nt) {
        int col = nt * 16 + m15;
        float bc = bt2[col];
        #pragma unroll
        for (int reg = 0; reg < 4; ++reg)
            smh[(wave * 16 + quad * 4 + reg) * 136 + col] = f2bf(accD[nt][reg] + bc);
    }
    __syncthreads();

    int col = tid;  // 0..127
    float acc8[8];
    #pragma unroll
    for (int k = 0; k < 8; ++k) acc8[k] = 0.f;
    int rmax = M - bid * 32;
    if (rmax > 32) rmax = 32;
    for (int rr = 0; rr < rmax; ++rr) {
        float t = bf2f(smh[rr * 136 + col]);
        const float4* sv4 = (const float4*)&SV[(size_t)(bid * 32 + rr) * 8];
        float4 s0 = sv4[0], s1 = sv4[1];
        acc8[0] += t * s0.x; acc8[1] += t * s0.y; acc8[2] += t * s0.z; acc8[3] += t * s0.w;
        acc8[4] += t * s1.x; acc8[5] += t * s1.y; acc8[6] += t * s1.z; acc8[7] += t * s1.w;
    }
    float e = 0.f;
    #pragma unroll
    for (int k = 0; k < 8; ++k) e += acc8[k] * W2[k * 128 + col];
    atomicAdd(&extraP[(bid & (XSLOT - 1)) * 128 + col], e);
}

template <int PACC>
__device__ __forceinline__ void body_out_mlp(int bid, unsigned short* smh,
                                             const unsigned short* hB,
                                             const unsigned short* W0t, const float* b0,
                                             const unsigned short* W1t, const float* b1,
                                             const float* w2col, const float* ob2p,
                                             float* Pout, int M) {
    int tid = threadIdx.x;
    int wave = tid >> 6, lane = tid & 63;
    int m15 = lane & 15, quad = lane >> 4;
    int row0 = bid * 32 + wave * 16;
    int arow = row0 + m15;
    if (arow > M - 1) arow = M - 1;
    unsigned short* L = smh + wave * (16 * 136);

    f32x4 acc[8];
    #pragma unroll
    for (int nt = 0; nt < 8; ++nt) acc[nt] = (f32x4){0.f, 0.f, 0.f, 0.f};
    #pragma unroll
    for (int kt = 0; kt < 4; ++kt) {
        int ks = kt * 32 + quad * 8;
        bf16x8 av = *(const bf16x8*)(hB + (size_t)arow * 128 + ks);
        #pragma unroll
        for (int nt = 0; nt < 8; ++nt) {
            bf16x8 bf = *(const bf16x8*)(W0t + (size_t)(nt * 16 + m15) * 128 + ks);
            acc[nt] = __builtin_amdgcn_mfma_f32_16x16x32_bf16(av, bf, acc[nt], 0, 0, 0);
        }
    }
    #pragma unroll
    for (int nt = 0; nt < 8; ++nt) {
        int col = nt * 16 + m15;
        float bc = b0[col];
        #pragma unroll
        for (int reg = 0; reg < 4; ++reg)
            L[(quad * 4 + reg) * 136 + col] = f2bf(siluf(acc[nt][reg] + bc));
    }
    __syncthreads();

    #pragma unroll
    for (int nt = 0; nt < 8; ++nt) acc[nt] = (f32x4){0.f, 0.f, 0.f, 0.f};
    #pragma unroll
    for (int kt = 0; kt < 4; ++kt) {
        int ks = kt * 32 + quad * 8;
        bf16x8 av = *(const bf16x8*)(L + m15 * 136 + ks);
        #pragma unroll
        for (int nt = 0; nt < 8; ++nt) {
            bf16x8 bf = *(const bf16x8*)(W1t + (size_t)(nt * 16 + m15) * 128 + ks);
            acc[nt] = __builtin_amdgcn_mfma_f32_16x16x32_bf16(av, bf, acc[nt], 0, 0, 0);
        }
    }
    float w2c[8], pp[4];
    #pragma unroll
    for (int nt = 0; nt < 8; ++nt) w2c[nt] = w2col[nt * 16 + m15];
    #pragma unroll
    for (int reg = 0; reg < 4; ++reg) pp[reg] = 0.f;
    #pragma unroll
    for (int nt = 0; nt < 8; ++nt) {
        float bc = b1[nt * 16 + m15];
        #pragma unroll
        for (int reg = 0; reg < 4; ++reg)
            pp[reg] += siluf(acc[nt][reg] + bc) * w2c[nt];
    }
    #pragma unroll
    for (int reg = 0; reg < 4; ++reg) {
        float s = pp[reg];
        s += __shfl_xor(s, 1, 64);
        s += __shfl_xor(s, 2, 64);
        s += __shfl_xor(s, 4, 64);
        s += __shfl_xor(s, 8, 64);
        if (m15 == 0) {
            int row = row0 + quad * 4 + reg;
            if (row < M) {
                float r = s + ob2p[0];
                if (PACC == 2) r += Pout[row];
                Pout[row] = r;
            }
        }
    }
}

// out_mlp(k=b) + block_mlp(b) in ONE kernel, sequential per block (same shape, shared LDS)
template <int PACC>
__global__ __launch_bounds__(128) void k_mlp2(const unsigned short* __restrict__ xh,
                                              const unsigned short* __restrict__ Wd, const float* __restrict__ bd,
                                              const unsigned short* __restrict__ Wt1,
                                              const unsigned short* __restrict__ Wt2, const float* __restrict__ bt2,
                                              const unsigned short* __restrict__ Wup, const float* __restrict__ bup,
                                              const float* __restrict__ SV, const float* __restrict__ W2,
                                              float* __restrict__ extraP, unsigned short* __restrict__ xuph,
                                              const unsigned short* __restrict__ hB,
                                              const unsigned short* __restrict__ W0t, const float* __restrict__ b0,
                                              const unsigned short* __restrict__ W1t, const float* __restrict__ b1,
                                              const float* __restrict__ w2col, const float* __restrict__ ob2p,
                                              float* __restrict__ Pout) {
    __shared__ unsigned short smh[2 * 16 * 136];
    body_block_mlp(blockIdx.x, smh, xh, Wd, bd, Wt1, Wt2, bt2, Wup, bup, SV, W2, extraP, xuph, N_);
    __syncthreads();
    body_out_mlp<PACC>(blockIdx.x, smh, hB, W0t, b0, W1t, b1, w2col, ob2p, Pout, N_);
}

// standalone out_mlp for the final out-block
__global__ __launch_bounds__(128) void k_out_mlp1(const unsigned short* __restrict__ hB,
                                                  const unsigned short* __restrict__ W0t, const float* __restrict__ b0,
                                                  const unsigned short* __restrict__ W1t, const float* __restrict__ b1,
                                                  const float* __restrict__ w2col, const float* __restrict__ ob2p,
                                                  float* __restrict__ Pout) {
    __shared__ unsigned short smh[2 * 16 * 136];
    body_out_mlp<2>(blockIdx.x, smh, hB, W0t, b0, W1t, b1, w2col, ob2p, Pout, N_);
}

// ================= out_block gather (256 thr / 4 nodes, unroll 4) =================
__global__ __launch_bounds__(256) void k_out_gather(const int* __restrict__ rowptr, const int* __restrict__ slist,
                                                    const float* __restrict__ rbfS,
                                                    const unsigned short* __restrict__ xh,
                                                    const float* __restrict__ wrbf,
                                                    unsigned short* __restrict__ hB, int n) {
    int node = blockIdx.x * 4 + (threadIdx.x >> 6);
    int lane = threadIdx.x & 63;
    if (node >= n) return;
    int c = lane * 2;
    float wc0[6], wc1[6];
    #pragma unroll
    for (int r = 0; r < 6; ++r) { wc0[r] = wrbf[r * 128 + c]; wc1[r] = wrbf[r * 128 + c + 1]; }
    float a0 = 0.f, a1 = 0.f;
    int p0 = rowptr[node], p1 = rowptr[node + 1];
    int p = p0;
    for (; p + 4 <= p1; p += 4) {
        int s0 = slist[p], s1 = slist[p + 1], s2 = slist[p + 2], s3 = slist[p + 3];
        float2 rb[4][3];
        #pragma unroll
        for (int u = 0; u < 4; ++u) {
            const float2* r2 = (const float2*)&rbfS[(size_t)(p + u) * 6];
            rb[u][0] = r2[0]; rb[u][1] = r2[1]; rb[u][2] = r2[2];
        }
        unsigned int xv0 = *(const unsigned int*)&xh[(size_t)s0 * 128 + c];
        unsigned int xv1 = *(const unsigned int*)&xh[(size_t)s1 * 128 + c];
        unsigned int xv2 = *(const unsigned int*)&xh[(size_t)s2 * 128 + c];
        unsigned int xv3 = *(const unsigned int*)&xh[(size_t)s3 * 128 + c];
        #pragma unroll
        for (int u = 0; u < 4; ++u) {
            float e0 = rb[u][0].x * wc0[0] + rb[u][0].y * wc0[1] + rb[u][1].x * wc0[2] +
                       rb[u][1].y * wc0[3] + rb[u][2].x * wc0[4] + rb[u][2].y * wc0[5];
            float e1 = rb[u][0].x * wc1[0] + rb[u][0].y * wc1[1] + rb[u][1].x * wc1[2] +
                       rb[u][1].y * wc1[3] + rb[u][2].x * wc1[4] + rb[u][2].y * wc1[5];
            float2 xf = bf2x2((u == 0) ? xv0 : (u == 1) ? xv1 : (u == 2) ? xv2 : xv3);
            a0 += xf.x * e0;
            a1 += xf.y * e1;
        }
    }
    for (; p < p1; ++p) {
        int src = slist[p];
        const float2* r2 = (const float2*)&rbfS[(size_t)p * 6];
        float2 ra = r2[0], rbx = r2[1], rc = r2[2];
        float e0 = ra.x * wc0[0] + ra.y * wc0[1] + rbx.x * wc0[2] + rbx.y * wc0[3] + rc.x * wc0[4] + rc.y * wc0[5];
        float e1 = ra.x * wc1[0] + ra.y * wc1[1] + rbx.x * wc1[2] + rbx.y * wc1[3] + rc.x * wc1[4] + rc.y * wc1[5];
        float2 xf = bf2x2(*(const unsigned int*)&xh[(size_t)src * 128 + c]);
        a0 += xf.x * e0;
        a1 += xf.y * e1;
    }
    *(unsigned int*)&hB[(size_t)node * 128 + c] = f2bf2(a0, a1);
}

// ================= interaction (256 thr / 4 nodes, unroll 4, XSLOT presum) =================
__global__ __launch_bounds__(256) void k_interact(const int* __restrict__ rowptr, const int* __restrict__ slist,
                                                  const __half* __restrict__ s8, const float* __restrict__ W2,
                                                  const float* __restrict__ extraP,
                                                  const unsigned short* __restrict__ xuph,
                                                  unsigned short* __restrict__ xh, int n) {
    __shared__ float exs[128];
    int tid = threadIdx.x;
    if (tid < 128) {
        float s = 0.f;
        #pragma unroll
        for (int q = 0; q < XSLOT; ++q) s += extraP[q * 128 + tid];
        exs[tid] = s;
    }
    __syncthreads();
    int node = blockIdx.x * 4 + (tid >> 6);
    int lane = tid & 63;
    if (node >= n) return;
    int c = lane * 2;
    f16x2 w2a[4], w2b[4];
    #pragma unroll
    for (int j = 0; j < 4; ++j) {
        f16x2 wa, wb;
        wa.x = (_Float16)W2[(2 * j) * 128 + c];
        wa.y = (_Float16)W2[(2 * j + 1) * 128 + c];
        wb.x = (_Float16)W2[(2 * j) * 128 + c + 1];
        wb.y = (_Float16)W2[(2 * j + 1) * 128 + c + 1];
        w2a[j] = wa;
        w2b[j] = wb;
    }
    int p0 = rowptr[node], p1 = rowptr[node + 1];
    float cntf = (float)(p1 - p0);
    float a0 = cntf * exs[c], a1 = cntf * exs[c + 1];
    int p = p0;
    for (; p + 4 <= p1; p += 4) {
        int s0 = slist[p], s1 = slist[p + 1], s2 = slist[p + 2], s3 = slist[p + 3];
        uint4 sv[4];
        #pragma unroll
        for (int u = 0; u < 4; ++u) sv[u] = *(const uint4*)(s8 + (size_t)(p + u) * 8);
        unsigned int xv0 = *(const unsigned int*)&xuph[(size_t)s0 * 128 + c];
        unsigned int xv1 = *(const unsigned int*)&xuph[(size_t)s1 * 128 + c];
        unsigned int xv2 = *(const unsigned int*)&xuph[(size_t)s2 * 128 + c];
        unsigned int xv3 = *(const unsigned int*)&xuph[(size_t)s3 * 128 + c];
        #pragma unroll
        for (int u = 0; u < 4; ++u) {
            union { uint4 q; f16x2 h[4]; } s;
            s.q = sv[u];
            float e0 = fdot2f(s.h[0], w2a[0], 0.f);
            e0 = fdot2f(s.h[1], w2a[1], e0);
            e0 = fdot2f(s.h[2], w2a[2], e0);
            e0 = fdot2f(s.h[3], w2a[3], e0);
            float e1 = fdot2f(s.h[0], w2b[0], 0.f);
            e1 = fdot2f(s.h[1], w2b[1], e1);
            e1 = fdot2f(s.h[2], w2b[2], e1);
            e1 = fdot2f(s.h[3], w2b[3], e1);
            float2 xf = bf2x2((u == 0) ? xv0 : (u == 1) ? xv1 : (u == 2) ? xv2 : xv3);
            a0 += xf.x * e0;
            a1 += xf.y * e1;
        }
    }
    for (; p < p1; ++p) {
        int src = slist[p];
        float2 xf = bf2x2(*(const unsigned int*)&xuph[(size_t)src * 128 + c]);
        union { uint4 q; f16x2 h[4]; } s;
        s.q = *(const uint4*)(s8 + (size_t)p * 8);
        float e0 = fdot2f(s.h[0], w2a[0], 0.f);
        e0 = fdot2f(s.h[1], w2a[1], e0);
        e0 = fdot2f(s.h[2], w2a[2], e0);
        e0 = fdot2f(s.h[3], w2a[3], e0);
        float e1 = fdot2f(s.h[0], w2b[0], 0.f);
        e1 = fdot2f(s.h[1], w2b[1], e1);
        e1 = fdot2f(s.h[2], w2b[2], e1);
        e1 = fdot2f(s.h[3], w2b[3], e1);
        a0 += xf.x * e0;
        a1 += xf.y * e1;
    }
    unsigned int cur = *(unsigned int*)&xh[(size_t)node * 128 + c];
    float2 xc = bf2x2(cur);
    *(unsigned int*)&xh[(size_t)node * 128 + c] = f2bf2(xc.x + a0, xc.y + a1);
}

// ================= pooling =================
__global__ __launch_bounds__(256) void k_pool(const float* __restrict__ P, const int* __restrict__ batch,
                                              float* __restrict__ pool, float* __restrict__ cnt, int n) {
    int i = blockIdx.x * 256 + threadIdx.x;
    int lane = threadIdx.x & 63;
    int b = (i < n) ? batch[i] : -1;
    float p = (i < n) ? P[i] : 0.f;
    int b0 = __shfl(b, 0, 64);
    int b63 = __shfl(b, 63, 64);
    if (b0 == b63 && b0 >= 0) {
        float s = p;
        #pragma unroll
        for (int off = 32; off > 0; off >>= 1) s += __shfl_xor(s, off, 64);
        if (lane == 0) {
            atomicAdd(&pool[b0], s);
            atomicAdd(&cnt[b0], 64.0f);
        }
    } else {
        if (i < n) {
            atomicAdd(&pool[b], p);
            atomicAdd(&cnt[b], 1.0f);
        }
    }
}

__global__ __launch_bounds__(64) void k_final(const float* __restrict__ pool, const float* __restrict__ cnt,
                                              float* __restrict__ out) {
    int g = threadIdx.x;
    if (g < G_) out[g] = __fdividef(pool[g], fmaxf(cnt[g], 1.0f));
}

extern "C" void kernel_launch(void* const* d_in, const int* in_sizes, int n_in,
                              void* d_out, int out_size, void* d_ws, size_t ws_size,
                              hipStream_t stream) {
    (void)in_sizes; (void)n_in; (void)out_size; (void)ws_size;
    const int* z = (const int*)d_in[0];
    const float* dist = (const float*)d_in[1];
    const float* dist_trip = (const float*)d_in[2];
    const float* angle = (const float*)d_in[3];
    const int* edge_index = (const int*)d_in[4];
    const int* triplets = (const int*)d_in[5];
    const int* batch = (const int*)d_in[6];
    const float* atom_table = (const float*)d_in[7];
    const float* rbf_freq = (const float*)d_in[8];
    const float* sbf_freq = (const float*)d_in[9];
    const float* emb_w1 = (const float*)d_in[10];
    const float* emb_b1 = (const float*)d_in[11];
    const float* emb_w2 = (const float*)d_in[12];
    const float* emb_b2 = (const float*)d_in[13];
    const float* iw_rbf1 = (const float*)d_in[14];
    const float* iw_rbf2 = (const float*)d_in[15];
    const float* iw_sbf1 = (const float*)d_in[16];
    const float* iw_sbf2 = (const float*)d_in[17];
    const float* iw_t1 = (const float*)d_in[18];
    const float* iw_t2 = (const float*)d_in[19];
    const float* ib_t2 = (const float*)d_in[20];
    const float* iw_up = (const float*)d_in[21];
    const float* ib_up = (const float*)d_in[22];
    const float* iw_down = (const float*)d_in[23];
    const float* ib_down = (const float*)d_in[24];
    const float* ow_rbf = (const float*)d_in[25];
    const float* ow0 = (const float*)d_in[26];
    const float* ob0 = (const float*)d_in[27];
    const float* ow1 = (const float*)d_in[28];
    const float* ob1 = (const float*)d_in[29];
    const float* ow2 = (const float*)d_in[30];
    const float* ob2 = (const float*)d_in[31];

    const int* erow = edge_index;
    const int* ecol = edge_index + E_;

    // workspace layout
    float* ws = (float*)d_ws;
    float* bufA = ws;                          // N*128 (embS bf16 out)
    float* bufB = bufA + (size_t)N_ * H_;      // N*128 (hB bf16)
    float* P = bufB + (size_t)N_ * H_;         // N
    float* rbfS = P + N_;                      // E*6 (CSR order)
    float* SV4 = rbfS + (size_t)E_ * 6;        // 4*N*8
    float* extra4 = SV4 + (size_t)4 * N_ * 8;  // 4 * XSLOT * 128
    float* pool = extra4 + 4 * XSLOT * 128;    // G
    float* cnt = pool + G_;                    // G
    int* bcntE = (int*)(cnt + G_);             // NSB
    int* bcntT = bcntE + NSB;                  // NSB
    int* bktbaseE = bcntT + NSB;               // NBK
    int* bktbaseT = bktbaseE + NBK;            // NBK
    int* rowptr = bktbaseT + NBK;              // N+1
    int* rowptrT = rowptr + N_ + 1;            // N+1
    int* slist = rowptrT + N_ + 1;             // E
    float* distS = (float*)(slist + E_);       // E
    uintptr_t tp = (uintptr_t)(distS + E_);
    tp = (tp + 7) & ~(uintptr_t)7;
    float2* tpay = (float2*)tp;                // T float2
    __half* s8all = (__half*)(tpay + T_);      // 4*E*8 halves
    __half* basis = s8all + (size_t)4 * E_ * 8;                          // T*24 halves
    unsigned short* xh = (unsigned short*)(basis + (size_t)T_ * 24);     // N*128 bf16 node state
    unsigned short* xuph = xh + (size_t)N_ * H_;                          // N*128 bf16 x_up
    unsigned short* Wt = xuph + (size_t)N_ * H_;                          // 27*16384 bf16 weights
    unsigned short* hB = (unsigned short*)bufB;

    // bucket arrays alias s8all region (written later by k_geomb) — 4B packed records
    unsigned int* ebkt = (unsigned int*)s8all;               // NSB*CAPS uint = 12.8MB
    unsigned int* tbkt = ebkt + (size_t)NSB * CAPS;          // NSB*CAPS uint = 12.8MB

    hipMemsetAsync(extra4, 0, (4 * XSLOT * 128 + 2 * G_ + 2 * NSB) * sizeof(float), stream);
    k_wprep<<<27 * 8, 256, 0, stream>>>(emb_w2, iw_down, iw_t1, iw_t2, iw_up, ow0, ow1, Wt);
    k_bucket<<<EB + TB, 256, 0, stream>>>(ecol, triplets, bcntE, ebkt, bcntT, tbkt);
    k_scanB<<<2, 1024, 0, stream>>>(bcntE, bktbaseE, bcntT, bktbaseT);
    k_place<<<2 * NBK, 256, 0, stream>>>(bcntE, ebkt, erow, dist, bktbaseE, rowptr, slist, distS,
                                         bcntT, tbkt, dist_trip, angle, bktbaseT, rowptrT, tpay);

    k_geomb<<<EG + TG, 256, 0, stream>>>(distS, rbf_freq, iw_rbf1, rbfS, s8all,
                                         tpay, sbf_freq, basis);
    k_embSix<<<NIX + NG2, 128, 0, stream>>>(atom_table, z, xh, rowptr, rbfS, emb_w1, emb_b1,
                                            (unsigned short*)bufA);
    k_gemmsv<<<GEMMG2 + SVG, 128, 0, stream>>>((unsigned short*)bufA, Wt, emb_b2, rowptr, xh,
                                               rowptrT, basis, iw_sbf1, SV4);

    // main loop: gather(b) -> [block_mlp(b) + out_mlp(b)] -> interact(b)
    for (int b = 0; b < 4; ++b) {
        k_out_gather<<<NG4, 256, 0, stream>>>(rowptr, slist, rbfS, xh,
                                              ow_rbf + (size_t)b * 6 * 128, hB, N_);
        if (b == 0)
            k_mlp2<1><<<GEMMG2, 128, 0, stream>>>(xh,
                                                  Wt + (size_t)(1 + b) * 16384, ib_down + b * 128,
                                                  Wt + (size_t)(5 + b) * 16384,
                                                  Wt + (size_t)(9 + b) * 16384, ib_t2 + b * 128,
                                                  Wt + (size_t)(13 + b) * 16384, ib_up + b * 128,
                                                  SV4 + (size_t)b * N_ * 8,
                                                  iw_sbf2 + (size_t)b * 1024,
                                                  extra4 + (size_t)b * XSLOT * 128, xuph,
                                                  hB, Wt + (size_t)(17 + b) * 16384, ob0 + b * 128,
                                                  Wt + (size_t)(22 + b) * 16384, ob1 + b * 128,
                                                  ow2 + b * 128, ob2 + b, P);
        else
            k_mlp2<2><<<GEMMG2, 128, 0, stream>>>(xh,
                                                  Wt + (size_t)(1 + b) * 16384, ib_down + b * 128,
                                                  Wt + (size_t)(5 + b) * 16384,
                                                  Wt + (size_t)(9 + b) * 16384, ib_t2 + b * 128,
                                                  Wt + (size_t)(13 + b) * 16384, ib_up + b * 128,
                                                  SV4 + (size_t)b * N_ * 8,
                                                  iw_sbf2 + (size_t)b * 1024,
                                                  extra4 + (size_t)b * XSLOT * 128, xuph,
                                                  hB, Wt + (size_t)(17 + b) * 16384, ob0 + b * 128,
                                                  Wt + (size_t)(22 + b) * 16384, ob1 + b * 128,
                                                  ow2 + b * 128, ob2 + b, P);
        k_interact<<<NG4, 256, 0, stream>>>(rowptr, slist, s8all + (size_t)b * E_ * 8,
                                            iw_rbf2 + (size_t)b * 1024, extra4 + (size_t)b * XSLOT * 128,
                                            xuph, xh, N_);
    }

    // final out_block (k = 4)
    k_out_gather<<<NG4, 256, 0, stream>>>(rowptr, slist, rbfS, xh,
                                          ow_rbf + (size_t)4 * 6 * 128, hB, N_);
    k_out_mlp1<<<GEMMG2, 128, 0, stream>>>(hB, Wt + (size_t)21 * 16384, ob0 + 4 * 128,
                                           Wt + (size_t)26 * 16384, ob1 + 4 * 128,
                                           ow2 + 4 * 128, ob2 + 4, P);

    k_pool<<<(N_ + 255) / 256, 256, 0, stream>>>(P, batch, pool, cnt, N_);
    k_final<<<1, 64, 0, stream>>>(pool, cnt, (float*)d_out);
}